// Round 7
// baseline (1997.706 us; speedup 1.0000x reference)
//
#include <hip/hip_runtime.h>
#include <stdint.h>

typedef unsigned long long u64;
typedef unsigned int u32;

#define TPB 256
#define NSMALL 9   // scales 2..10 batched
#define NSC 11

__device__ __forceinline__ int findJob(const int* cum, int nj, int v) {
  int j = 0;
  while (j + 1 < nj && v >= cum[j + 1]) ++j;
  return j;
}

// ---------------- resize weight tables (per scale, per output position) -----
struct MkP { int ns; int nw[NSC]; float invs[NSC], ks[NSC];
             int oxB[NSC], T[NSC], wOff[NSC]; };

__global__ void k_mkweights(int* __restrict__ tX0, int* __restrict__ tCNT,
                            float* __restrict__ tWT, float* __restrict__ tW, MkP P) {
  const int s = blockIdx.x;
  const int nw = P.nw[s];
  const float invs = P.invs[s], ks = P.ks[s];
  const int T = P.T[s];
  for (int ox = threadIdx.x; ox < nw; ox += TPB) {
    float sx = ((float)ox + 0.5f) * invs - 0.5f;
    int x0 = (int)ceilf(sx - ks); if (x0 < 0) x0 = 0;
    int x1 = (int)floorf(sx + ks); if (x1 > 767) x1 = 767;
    float wt = 0.f;
    float* wv = tW + P.wOff[s] + (long)ox * T;
    for (int j = x0; j <= x1; ++j) {
      float w = fmaxf(0.f, 1.f - fabsf(sx - (float)j) / ks);
      wt += w;
      wv[j - x0] = w;
    }
    for (int k = x1 - x0 + 1; k < T; ++k) wv[k] = 0.f;
    int g = P.oxB[s] + ox;
    tX0[g] = x0; tCNT[g] = x1 - x0 + 1; tWT[g] = wt;
  }
}

// ---------------- per-scale resize kernels (big scales 0,1) -----------------
__global__ void k_resizeHrow(const float* __restrict__ img, float* __restrict__ tmp,
                             int nw, int oxB, int T, int wOff,
                             const int* __restrict__ tX0, const int* __restrict__ tCNT,
                             const float* __restrict__ tWT, const float* __restrict__ tW) {
  __shared__ float row[3][768];
  const int y = blockIdx.x, b = blockIdx.y;
  const float* src = img + ((long)b * 768 + y) * 768 * 3;
  for (int t = threadIdx.x; t < 2304; t += TPB) {
    int x = t / 3, c = t - 3 * x;
    row[c][x] = src[t];
  }
  __syncthreads();
  const int total = 3 * nw;
  for (int t = threadIdx.x; t < total; t += TPB) {
    int ox = t % nw, c = t / nw;
    int g = oxB + ox;
    int x0 = tX0[g], cnt = tCNT[g];
    float wt = tWT[g];
    const float* wv = tW + wOff + (long)ox * T;
    float acc = 0.f;
    for (int k = 0; k < cnt; ++k) acc += row[c][x0 + k] * wv[k];
    tmp[(((long)b * 3 + c) * 768 + y) * nw + ox] = acc / wt;
  }
}

__global__ void k_resizeV(const float* __restrict__ tmp, float* __restrict__ out,
                          int nh, int nw, int oxB, int T, int wOff,
                          const int* __restrict__ tX0, const int* __restrict__ tCNT,
                          const float* __restrict__ tWT, const float* __restrict__ tW) {
  long idx = (long)blockIdx.x * blockDim.x + threadIdx.x;
  long total = (long)8 * 3 * nh * nw;
  if (idx >= total) return;
  int ox = (int)(idx % nw); long t = idx / nw;
  int oy = (int)(t % nh); t /= nh;
  int c = (int)(t % 3); int b = (int)(t / 3);
  int g = oxB + oy;
  int y0 = tX0[g], cnt = tCNT[g];
  float wt = tWT[g];
  const float* wv = tW + wOff + (long)oy * T;
  const float* col = tmp + ((long)(b * 3 + c) * 768) * nw + ox;
  float acc = 0.f;
  for (int k = 0; k < cnt; ++k) acc += col[(long)(y0 + k) * nw] * wv[k];
  out[(((long)b * 3 + c) * nh + oy) * nw + ox] = (acc / wt - 127.5f) * 0.0078125f;
}

// ---------------- batched resize, scales 2..10 ------------------------------
struct HallP { int nj; int nw[NSMALL]; int hOff[NSMALL]; int cumW[NSMALL + 1];
               int oxB[NSMALL], T[NSMALL], wOff[NSMALL]; };

__global__ void k_resizeH_all(const float* __restrict__ img, float* __restrict__ base,
                              const int* __restrict__ tX0, const int* __restrict__ tCNT,
                              const float* __restrict__ tWT, const float* __restrict__ tW,
                              HallP P) {
  __shared__ float row[3][768];
  const int y = blockIdx.x, b = blockIdx.y;
  const float* src = img + ((long)b * 768 + y) * 768 * 3;
  for (int t = threadIdx.x; t < 2304; t += TPB) {
    int x = t / 3, c = t - 3 * x;
    row[c][x] = src[t];
  }
  __syncthreads();
  const int total = P.cumW[P.nj];
  for (int t = threadIdx.x; t < total; t += TPB) {
    int j = findJob(P.cumW, P.nj, t);
    int local = t - P.cumW[j];
    int nw = P.nw[j];
    int ox = local % nw, c = local / nw;
    int g = P.oxB[j] + ox;
    int x0 = tX0[g], cnt = tCNT[g];
    float wt = tWT[g];
    const float* wv = tW + P.wOff[j] + (long)ox * P.T[j];
    float acc = 0.f;
    for (int k = 0; k < cnt; ++k) acc += row[c][x0 + k] * wv[k];
    base[P.hOff[j] + (((long)b * 3 + c) * 768 + y) * nw + ox] = acc / wt;
  }
}

struct VallP { int nj; int nh[NSMALL], nw[NSMALL];
               int hOff[NSMALL], imgOff[NSMALL]; int cumE[NSMALL + 1];
               int oxB[NSMALL], T[NSMALL], wOff[NSMALL]; };

__global__ void k_resizeV_all(const float* __restrict__ base, float* __restrict__ img,
                              const int* __restrict__ tX0, const int* __restrict__ tCNT,
                              const float* __restrict__ tWT, const float* __restrict__ tW,
                              VallP P) {
  int gid = blockIdx.x * TPB + threadIdx.x;
  if (gid >= P.cumE[P.nj]) return;
  int j = findJob(P.cumE, P.nj, gid);
  int local = gid - P.cumE[j];
  int nh = P.nh[j], nw = P.nw[j];
  int ox = local % nw; int t = local / nw;
  int oy = t % nh; t /= nh;
  int c = t % 3; int b = t / 3;
  int g = P.oxB[j] + oy;
  int y0 = tX0[g], cnt = tCNT[g];
  float wt = tWT[g];
  const float* wv = tW + P.wOff[j] + (long)oy * P.T[j];
  const float* col = base + P.hOff[j] + ((long)(b * 3 + c) * 768) * nw + ox;
  float acc = 0.f;
  for (int k = 0; k < cnt; ++k) acc += col[(long)(y0 + k) * nw] * wv[k];
  img[P.imgOff[j] + (((long)b * 3 + c) * nh + oy) * nw + ox] =
      (acc / wt - 127.5f) * 0.0078125f;
}

// ---------------- fused conv1 + PReLU + 2x2 ceil-maxpool --------------------
__device__ __forceinline__ void conv1pool_body(
    const float* in, const float* w, const float* bias, const float* pr,
    float* out, int H, int W, int co, int b, int px, int py) {
  const int h1 = H - 2, w1 = W - 2;
  const int PH = (h1 + 1) >> 1, PW = (w1 + 1) >> 1;
  if (px >= PW || py >= PH) return;
  const int x0 = px * 2, y0 = py * 2;
  float a00 = 0.f, a01 = 0.f, a10 = 0.f, a11 = 0.f;
  const float* wp = w + (long)co * 27;
  const long HW = (long)H * W;
  const float* pp = in + ((long)b * 3 * H + y0) * W + x0;
  for (int ci = 0; ci < 3; ++ci, pp += HW) {
    const float* r = pp;
    float r00 = r[0], r01 = r[1], r02 = r[2], r03 = r[3]; r += W;
    float r10 = r[0], r11 = r[1], r12 = r[2], r13 = r[3]; r += W;
    float r20 = r[0], r21 = r[1], r22 = r[2], r23 = r[3]; r += W;
    float r30 = r[0], r31 = r[1], r32 = r[2], r33 = r[3];
    const float* wc = wp + ci * 9;
    float w0 = wc[0], w1_ = wc[1], w2 = wc[2];
    float w3 = wc[3], w4 = wc[4], w5 = wc[5];
    float w6 = wc[6], w7 = wc[7], w8 = wc[8];
    a00 += r00 * w0 + r01 * w1_ + r02 * w2;
    a00 += r10 * w3 + r11 * w4 + r12 * w5;
    a00 += r20 * w6 + r21 * w7 + r22 * w8;
    a01 += r01 * w0 + r02 * w1_ + r03 * w2;
    a01 += r11 * w3 + r12 * w4 + r13 * w5;
    a01 += r21 * w6 + r22 * w7 + r23 * w8;
    a10 += r10 * w0 + r11 * w1_ + r12 * w2;
    a10 += r20 * w3 + r21 * w4 + r22 * w5;
    a10 += r30 * w6 + r31 * w7 + r32 * w8;
    a11 += r11 * w0 + r12 * w1_ + r13 * w2;
    a11 += r21 * w3 + r22 * w4 + r23 * w5;
    a11 += r31 * w6 + r32 * w7 + r33 * w8;
  }
  const float bb = bias[co], al = pr[co];
  const bool vx = (x0 + 1 < w1), vy = (y0 + 1 < h1);
  float v = a00 + bb; v = v > 0.f ? v : al * v;
  float m = v;
  if (vx) { v = a01 + bb; v = v > 0.f ? v : al * v; m = fmaxf(m, v); }
  if (vy) { v = a10 + bb; v = v > 0.f ? v : al * v; m = fmaxf(m, v); }
  if (vx && vy) { v = a11 + bb; v = v > 0.f ? v : al * v; m = fmaxf(m, v); }
  out[(((long)b * 10 + co) * PH + py) * PW + px] = m;
}

__global__ void k_conv1pool(const float* __restrict__ in, const float* __restrict__ w,
                            const float* __restrict__ bias, const float* __restrict__ pr,
                            float* __restrict__ out, int H, int W, int tilesX) {
  const int tX = blockIdx.x % tilesX, tY = blockIdx.x / tilesX;
  conv1pool_body(in, w, bias, pr, out, H, W, blockIdx.y, blockIdx.z,
                 tX * 16 + (threadIdx.x & 15), tY * 16 + (threadIdx.x >> 4));
}

struct C1P { int nj; int nh[NSMALL], nw[NSMALL]; int imgOff[NSMALL], poolOff[NSMALL];
             int t1x[NSMALL]; int cumT[NSMALL + 1]; };

__global__ void k_conv1pool_job(const float* __restrict__ imgb, const float* __restrict__ w,
                                const float* __restrict__ bias, const float* __restrict__ pr,
                                float* __restrict__ poolb, C1P P) {
  int j = findJob(P.cumT, P.nj, blockIdx.x);
  int local = blockIdx.x - P.cumT[j];
  int t1x = P.t1x[j];
  int tX = local % t1x, tY = local / t1x;
  conv1pool_body(imgb + P.imgOff[j], w, bias, pr, poolb + P.poolOff[j],
                 P.nh[j], P.nw[j], blockIdx.y, blockIdx.z,
                 tX * 16 + (threadIdx.x & 15), tY * 16 + (threadIdx.x >> 4));
}

// ---------------- co-blocked tiled 3x3 conv + PReLU -------------------------
__device__ __forceinline__ void conv3x3c8_body(
    const float* in, const float* w, const float* bias, const float* pr,
    float* out, int Cin, int Cout, int H, int W, int cog, int b, int x0, int y) {
  const int OH = H - 2, OW = W - 2;
  if (y >= OH || x0 >= OW) return;
  float acc[8][4];
#pragma unroll
  for (int k = 0; k < 8; ++k) { acc[k][0] = 0.f; acc[k][1] = 0.f; acc[k][2] = 0.f; acc[k][3] = 0.f; }
  const float* wp = w + (long)cog * Cin * 9;
  const long HW = (long)H * W;
  const float* pp = in + ((long)b * Cin * H + y) * W + x0;
  for (int ci = 0; ci < Cin; ++ci, pp += HW) {
    const float* r = pp;
    float q00 = r[0], q01 = r[1], q02 = r[2], q03 = r[3], q04 = r[4], q05 = r[5]; r += W;
    float q10 = r[0], q11 = r[1], q12 = r[2], q13 = r[3], q14 = r[4], q15 = r[5]; r += W;
    float q20 = r[0], q21 = r[1], q22 = r[2], q23 = r[3], q24 = r[4], q25 = r[5];
#pragma unroll
    for (int k = 0; k < 8; ++k) {
      const float* wc = wp + ((long)k * Cin + ci) * 9;
      float w0 = wc[0], w1 = wc[1], w2 = wc[2];
      float w3 = wc[3], w4 = wc[4], w5 = wc[5];
      float w6 = wc[6], w7 = wc[7], w8 = wc[8];
      acc[k][0] += q00 * w0 + q01 * w1 + q02 * w2;
      acc[k][1] += q01 * w0 + q02 * w1 + q03 * w2;
      acc[k][2] += q02 * w0 + q03 * w1 + q04 * w2;
      acc[k][3] += q03 * w0 + q04 * w1 + q05 * w2;
      acc[k][0] += q10 * w3 + q11 * w4 + q12 * w5;
      acc[k][1] += q11 * w3 + q12 * w4 + q13 * w5;
      acc[k][2] += q12 * w3 + q13 * w4 + q14 * w5;
      acc[k][3] += q13 * w3 + q14 * w4 + q15 * w5;
      acc[k][0] += q20 * w6 + q21 * w7 + q22 * w8;
      acc[k][1] += q21 * w6 + q22 * w7 + q23 * w8;
      acc[k][2] += q22 * w6 + q23 * w7 + q24 * w8;
      acc[k][3] += q23 * w6 + q24 * w7 + q25 * w8;
    }
  }
  const int rem = OW - x0;
#pragma unroll
  for (int k = 0; k < 8; ++k) {
    const int co = cog + k;
    const float bb = bias[co], al = pr[co];
    float* op = out + (((long)b * Cout + co) * OH + y) * OW + x0;
    float v0 = acc[k][0] + bb; v0 = v0 > 0.f ? v0 : al * v0;
    op[0] = v0;
    if (rem > 1) { float v = acc[k][1] + bb; v = v > 0.f ? v : al * v; op[1] = v; }
    if (rem > 2) { float v = acc[k][2] + bb; v = v > 0.f ? v : al * v; op[2] = v; }
    if (rem > 3) { float v = acc[k][3] + bb; v = v > 0.f ? v : al * v; op[3] = v; }
  }
}

__global__ void k_conv3x3c8(const float* __restrict__ in, const float* __restrict__ w,
                            const float* __restrict__ bias, const float* __restrict__ pr,
                            float* __restrict__ out, int Cin, int Cout, int H, int W,
                            int tilesX) {
  const int tX = blockIdx.x % tilesX, tY = blockIdx.x / tilesX;
  conv3x3c8_body(in, w, bias, pr, out, Cin, Cout, H, W, blockIdx.y * 8, blockIdx.z,
                 tX * 64 + (threadIdx.x & 15) * 4, tY * 16 + (threadIdx.x >> 4));
}

struct CvP { int nj; int H[NSMALL], W[NSMALL]; int inOff[NSMALL], outOff[NSMALL];
             int tx[NSMALL]; int cumT[NSMALL + 1]; };

__global__ void k_conv3x3c8_job(const float* __restrict__ inb, const float* __restrict__ w,
                                const float* __restrict__ bias, const float* __restrict__ pr,
                                float* __restrict__ outb, int Cin, int Cout, CvP P) {
  int j = findJob(P.cumT, P.nj, blockIdx.x);
  int local = blockIdx.x - P.cumT[j];
  int tx0 = P.tx[j];
  int tX = local % tx0, tY = local / tx0;
  conv3x3c8_body(inb + P.inOff[j], w, bias, pr, outb + P.outOff[j], Cin, Cout,
                 P.H[j], P.W[j], blockIdx.y * 8, blockIdx.z,
                 tX * 64 + (threadIdx.x & 15) * 4, tY * 16 + (threadIdx.x >> 4));
}

// ---------------- 1x1 heads -------------------------------------------------
__device__ __forceinline__ void head_body(const float* x3, const float* w41,
                                          const float* b41, const float* w42,
                                          const float* b42, float* reg, u64* keys,
                                          int plane, long idx) {
  int b = (int)(idx / plane); int rem = (int)(idx % plane);
  const float* p = x3 + (long)b * 32 * plane + rem;
  float l0 = 0.f, l1 = 0.f, r0 = 0.f, r1 = 0.f, r2 = 0.f, r3 = 0.f;
  for (int c = 0; c < 32; ++c) {
    float v = p[(long)c * plane];
    l0 += v * w41[c];      l1 += v * w41[32 + c];
    r0 += v * w42[c];      r1 += v * w42[32 + c];
    r2 += v * w42[64 + c]; r3 += v * w42[96 + c];
  }
  l0 += b41[0]; l1 += b41[1];
  r0 += b42[0]; r1 += b42[1]; r2 += b42[2]; r3 += b42[3];
  float mx = fmaxf(l0, l1);
  float e0 = expf(l0 - mx), e1 = expf(l1 - mx);
  float s = e1 / (e0 + e1);
  reg[idx * 4 + 0] = r0; reg[idx * 4 + 1] = r1;
  reg[idx * 4 + 2] = r2; reg[idx * 4 + 3] = r3;
  u32 ic = 0xFFFFFFFFu - (u32)idx;
  u64 k = (s >= 0.6f) ? ((((u64)__float_as_uint(s)) << 32) | ic) : (u64)ic;
  keys[idx] = k;
}

__global__ void k_head(const float* __restrict__ x3, const float* __restrict__ w41,
                       const float* __restrict__ b41, const float* __restrict__ w42,
                       const float* __restrict__ b42, float* __restrict__ reg,
                       u64* __restrict__ keys, int H, int W) {
  long plane = (long)H * W;
  long idx = (long)blockIdx.x * blockDim.x + threadIdx.x;
  if (idx >= 8 * plane) return;
  head_body(x3, w41, b41, w42, b42, reg, keys, (int)plane, idx);
}

struct HdP { int nj; int h3[NSMALL], w3[NSMALL]; int c3Off[NSMALL], kOff[NSMALL];
             int cumC[NSMALL + 1]; };

__global__ void k_head_job(const float* __restrict__ c3b, const float* __restrict__ w41,
                           const float* __restrict__ b41, const float* __restrict__ w42,
                           const float* __restrict__ b42, float* __restrict__ regb,
                           u64* __restrict__ keysb, HdP P) {
  int gid = blockIdx.x * TPB + threadIdx.x;
  if (gid >= P.cumC[P.nj]) return;
  int j = findJob(P.cumC, P.nj, gid);
  int idx = gid - P.cumC[j];
  head_body(c3b + P.c3Off[j], w41, b41, w42, b42,
            regb + 4L * P.kOff[j], keysb + P.kOff[j], P.h3[j] * P.w3[j], idx);
}

// ---------------- bitonic top-K ---------------------------------------------
__device__ __forceinline__ void bitonic2048(u64* s) {
  for (int k = 2; k <= 2048; k <<= 1) {
    for (int j = k >> 1; j > 0; j >>= 1) {
      for (int i = threadIdx.x; i < 2048; i += TPB) {
        int ixj = i ^ j;
        if (ixj > i) {
          u64 a = s[i], b = s[ixj];
          bool desc = ((i & k) == 0);
          if (desc ? (a < b) : (a > b)) { s[i] = b; s[ixj] = a; }
        }
      }
      __syncthreads();
    }
  }
}

__global__ void k_topk(const u64* __restrict__ in, int n, u64* __restrict__ out, int K) {
  __shared__ u64 s[2048];
  int base = blockIdx.x * 2048;
  for (int t = threadIdx.x; t < 2048; t += TPB) {
    int gi = base + t;
    s[t] = (gi < n) ? in[gi] : 0ULL;
  }
  __syncthreads();
  bitonic2048(s);
  for (int t = threadIdx.x; t < K; t += TPB)
    out[(long)blockIdx.x * K + t] = s[t];
}

struct TkP { int nj; int srcSel[NSMALL]; int srcOff[NSMALL]; int n[NSMALL];
             int dstOff[NSMALL]; int cumB[NSMALL + 1]; };

__global__ void k_topk_job(u64* __restrict__ A, u64* __restrict__ B, TkP P) {
  __shared__ u64 s[2048];
  int j = findJob(P.cumB, P.nj, blockIdx.x);
  int lb = blockIdx.x - P.cumB[j];
  const u64* src = (P.srcSel[j] ? B : A) + P.srcOff[j];
  u64* dst = (P.srcSel[j] ? A : B) + P.dstOff[j];
  int n = P.n[j];
  int base = lb * 2048;
  for (int t = threadIdx.x; t < 2048; t += TPB) {
    int gi = base + t;
    s[t] = (gi < n) ? src[gi] : 0ULL;
  }
  __syncthreads();
  bitonic2048(s);
  for (int t = threadIdx.x; t < 512; t += TPB)
    dst[(long)lb * 512 + t] = s[t];
}

struct TkFP { int nj; int srcSel[NSMALL]; int srcOff[NSMALL]; int n[NSMALL]; };

__global__ void k_topk_fin(const u64* __restrict__ A, const u64* __restrict__ B,
                           u64* __restrict__ selk, TkFP P) {
  __shared__ u64 s[2048];
  int j = blockIdx.x;
  const u64* src = (P.srcSel[j] ? B : A) + P.srcOff[j];
  int n = P.n[j];
  for (int t = threadIdx.x; t < 2048; t += TPB)
    s[t] = (t < n) ? src[t] : 0ULL;
  __syncthreads();
  bitonic2048(s);
  for (int t = threadIdx.x; t < 512; t += TPB)
    selk[(long)(j + 2) * 512 + t] = s[t];
}

// ---------------- gather box rows -------------------------------------------
__device__ __forceinline__ void gather_body(const u64* keys, const float* reg,
                                            float* boxes, int h, int w, float scalef,
                                            int i) {
  float* bx = boxes + (long)i * 12;
  u64 key = keys[i];
  if ((key >> 32) == 0ULL) {
    for (int q = 0; q < 12; ++q) bx[q] = 0.f;
    return;
  }
  u32 cell = 0xFFFFFFFFu - (u32)(key & 0xFFFFFFFFu);
  int x = (int)(cell % (u32)w); u32 t2 = cell / (u32)w;
  int y = (int)(t2 % (u32)h); int b = (int)(t2 / (u32)h);
  float fx = (float)x, fy = (float)y;
  bx[0] = floorf((2.f * fx + 1.f) / scalef);
  bx[1] = floorf((2.f * fy + 1.f) / scalef);
  bx[2] = floorf((2.f * fx + 12.f) / scalef);
  bx[3] = floorf((2.f * fy + 12.f) / scalef);
  bx[4] = __uint_as_float((u32)(key >> 32));
  bx[5] = reg[(long)cell * 4 + 0];
  bx[6] = reg[(long)cell * 4 + 1];
  bx[7] = reg[(long)cell * 4 + 2];
  bx[8] = reg[(long)cell * 4 + 3];
  bx[9] = (float)b;
  bx[10] = 1.f;
  bx[11] = 0.f;
}

__global__ void k_gather(const u64* __restrict__ keys, const float* __restrict__ reg,
                         float* __restrict__ boxes, int h, int w, float scalef) {
  int i = blockIdx.x * blockDim.x + threadIdx.x;
  if (i >= 512) return;
  gather_body(keys, reg, boxes, h, w, scalef, i);
}

struct GtP { int nj; int h3[NSMALL], w3[NSMALL]; float scalef[NSMALL]; int kOff[NSMALL]; };

__global__ void k_gather_job(const u64* __restrict__ selk, const float* __restrict__ regb,
                             float* __restrict__ boxes, GtP P) {
  int j = blockIdx.x >> 1;
  int i = ((blockIdx.x & 1) << 8) + threadIdx.x;
  gather_body(selk + (long)(j + 2) * 512, regb + 4L * P.kOff[j],
              boxes + (long)(j + 2) * 512 * 12, P.h3[j], P.w3[j], P.scalef[j], i);
}

// ---------------- greedy NMS ------------------------------------------------
__global__ void k_nms(float* __restrict__ boxes, int per, float thr) {
  __shared__ float sx1[1024], sy1[1024], sx2[1024], sy2[1024], sar[1024];
  __shared__ unsigned char kp[1024];
  __shared__ int snv;
  float* bs = boxes + (long)blockIdx.x * per * 12;
  int N = per;
  if (threadIdx.x == 0) snv = 0;
  __syncthreads();
  for (int i = threadIdx.x; i < N; i += blockDim.x) {
    const float* b = bs + (long)i * 12;
    float off = b[9] * 100000.0f;
    float a0 = b[0] + off, a1 = b[1] + off, a2 = b[2] + off, a3 = b[3] + off;
    sx1[i] = a0; sy1[i] = a1; sx2[i] = a2; sy2[i] = a3;
    sar[i] = fmaxf(a2 - a0, 0.f) * fmaxf(a3 - a1, 0.f);
    bool v = (b[10] != 0.f);
    kp[i] = v;
    if (v) atomicMax(&snv, i + 1);
  }
  __syncthreads();
  int nv = snv;
  for (int i = 0; i < nv; ++i) {
    if (kp[i]) {
      float xi1 = sx1[i], yi1 = sy1[i], xi2 = sx2[i], yi2 = sy2[i], ai = sar[i];
      for (int j = threadIdx.x; j < nv; j += blockDim.x) {
        if (j > i && kp[j]) {
          float iw = fmaxf(fminf(xi2, sx2[j]) - fmaxf(xi1, sx1[j]), 0.f);
          float ih = fmaxf(fminf(yi2, sy2[j]) - fmaxf(yi1, sy1[j]), 0.f);
          float inter = iw * ih;
          float iou = inter / (ai + sar[j] - inter + 1e-9f);
          if (iou > thr) kp[j] = 0;
        }
      }
    }
    __syncthreads();
  }
  for (int i = threadIdx.x; i < N; i += blockDim.x)
    bs[(long)i * 12 + 11] = kp[i] ? 1.f : 0.f;
}

// ---------------- final stage ------------------------------------------------
__global__ void k_finalkeys(const float* __restrict__ boxes, u64* __restrict__ keys,
                            int total, int padded) {
  int i = blockIdx.x * blockDim.x + threadIdx.x;
  if (i >= padded) return;
  u64 k = 0ULL;
  if (i < total) {
    const float* b = boxes + (long)i * 12;
    u32 ic = 0xFFFFFFFFu - (u32)i;
    k = (b[11] != 0.f) ? ((((u64)__float_as_uint(b[4])) << 32) | ic) : (u64)ic;
  }
  keys[i] = k;
}

__global__ void k_gatherfinal(const u64* __restrict__ keys, const float* __restrict__ boxes,
                              float* __restrict__ sel) {
  int i = blockIdx.x * blockDim.x + threadIdx.x;
  if (i >= 1024) return;
  u64 key = keys[i];
  float* o = sel + (long)i * 12;
  if ((key >> 32) == 0ULL) {
    for (int q = 0; q < 12; ++q) o[q] = 0.f;
    return;
  }
  u32 bi = 0xFFFFFFFFu - (u32)(key & 0xFFFFFFFFu);
  const float* b = boxes + (long)bi * 12;
  for (int q = 0; q < 12; ++q) o[q] = b[q];
  o[10] = 1.f;
  o[11] = 0.f;
}

__global__ void k_refine(const float* __restrict__ sel, float* __restrict__ out, int N) {
  int i = blockIdx.x * blockDim.x + threadIdx.x;
  if (i >= N) return;
  const float* b = sel + (long)i * 12;
  float keep = b[11];
  float x1 = b[0], y1 = b[1], x2 = b[2], y2 = b[3], sc = b[4];
  float rw = x2 - x1, rh = y2 - y1;
  float o0 = x1 + b[5] * rw;
  float o1 = y1 + b[6] * rh;
  float o2 = x2 + b[7] * rw;
  float o3 = y2 + b[8] * rh;
  float hh = o3 - o1, ww = o2 - o0;
  float l = fmaxf(hh, ww);
  float nx1 = o0 + ww * 0.5f - l * 0.5f;
  float ny1 = o1 + hh * 0.5f - l * 0.5f;
  out[(long)i * 5 + 0] = nx1 * keep;
  out[(long)i * 5 + 1] = ny1 * keep;
  out[(long)i * 5 + 2] = (nx1 + l) * keep;
  out[(long)i * 5 + 3] = (ny1 + l) * keep;
  out[(long)i * 5 + 4] = sc * keep;
}

extern "C" void kernel_launch(void* const* d_in, const int* in_sizes, int n_in,
                              void* d_out, int out_size, void* d_ws, size_t ws_size,
                              hipStream_t stream) {
  (void)in_sizes; (void)n_in; (void)out_size; (void)ws_size;
  const float* images = (const float*)d_in[0];
  const float* c1w = (const float*)d_in[1];
  const float* c1b = (const float*)d_in[2];
  const float* p1  = (const float*)d_in[3];
  const float* c2w = (const float*)d_in[4];
  const float* c2b = (const float*)d_in[5];
  const float* p2  = (const float*)d_in[6];
  const float* c3w = (const float*)d_in[7];
  const float* c3b = (const float*)d_in[8];
  const float* p3  = (const float*)d_in[9];
  const float* w41 = (const float*)d_in[10];
  const float* b41 = (const float*)d_in[11];
  const float* w42 = (const float*)d_in[12];
  const float* b42 = (const float*)d_in[13];
  float* ws = (float*)d_ws;

  const long O_IMG  = 0;
  const long O_C1   = 5101008;
  const long O_POOL = O_C1 + 16854496;
  const long O_C2   = O_POOL + 4232000;
  const long O_REG  = O_C2 + 6653952;
  const long O_KA   = O_REG + 1634432;
  const long O_KB   = O_KA + 817216;
  const long O_SEL  = O_KB + 204800;
  const long O_BOX  = O_SEL + 11264;
  const long O_FK   = O_BOX + 67584;
  const long O_FS   = O_FK + 16384;
  const long O_SF   = O_FS + 2048;
  // weight tables live in the dead tail of O_C1 (max O_C1 usage = 14.08M floats)
  const long O_TBL  = O_C1 + 16000000;

  u64* keysA = (u64*)(ws + O_KA);
  u64* keysB = (u64*)(ws + O_KB);
  u64* selk  = (u64*)(ws + O_SEL);
  u64* fkeys = (u64*)(ws + O_FK);
  u64* fsel  = (u64*)(ws + O_FS);
  float* boxes = ws + O_BOX;
  float* self  = ws + O_SF;
  int*   tX0  = (int*)(ws + O_TBL);
  int*   tCNT = (int*)(ws + O_TBL + 4096);
  float* tWT  = ws + O_TBL + 8192;
  float* tW   = ws + O_TBL + 12288;

  double scl[16]; int nsc = 0;
  {
    double m = 12.0 / 20.0;
    double ml = 768.0 * m;
    double si = m;
    while (ml >= 12.0) { scl[nsc++] = si; si *= 0.709; ml *= 0.709; }
  }

  auto cdiv = [](long a, long b) { return (int)((a + b - 1) / b); };

  // per-scale dims + table geometry
  int NH[NSC], PH_[NSC], H2[NSC], H3[NSC], OXB[NSC], TT[NSC], WOFF[NSC];
  float INV[NSC], KSF[NSC];
  {
    int oxb = 0, woff = 0;
    for (int s = 0; s < nsc; ++s) {
      int nh = (int)(768.0 * scl[s] + 1.0);
      NH[s] = nh;
      PH_[s] = ((nh - 2) + 1) / 2;
      H2[s] = PH_[s] - 2;
      H3[s] = H2[s] - 2;
      double inv = 1.0 / (((double)nh) / 768.0);
      INV[s] = (float)inv;
      KSF[s] = (float)(inv > 1.0 ? inv : 1.0);
      TT[s] = (int)(2.0f * KSF[s]) + 2;
      OXB[s] = oxb; oxb += nh;
      WOFF[s] = woff; woff += nh * TT[s];
    }
  }

  // build resize weight tables (once per launch)
  {
    MkP P; P.ns = nsc;
    for (int s = 0; s < nsc; ++s) {
      P.nw[s] = NH[s]; P.invs[s] = INV[s]; P.ks[s] = KSF[s];
      P.oxB[s] = OXB[s]; P.T[s] = TT[s]; P.wOff[s] = WOFF[s];
    }
    k_mkweights<<<nsc, TPB, 0, stream>>>(tX0, tCNT, tWT, tW, P);
  }

  // ---------------- big scales 0,1: per-scale chains ----------------
  for (int s = 0; s < 2; ++s) {
    int nh = NH[s], nw = nh;
    {
      dim3 gh(768, 8, 1);
      k_resizeHrow<<<gh, TPB, 0, stream>>>(images, ws + O_C1, nw,
                                           OXB[s], TT[s], WOFF[s], tX0, tCNT, tWT, tW);
    }
    k_resizeV<<<cdiv((long)8 * 3 * nh * nw, TPB), TPB, 0, stream>>>(
        ws + O_C1, ws + O_IMG, nh, nw, OXB[s], TT[s], WOFF[s], tX0, tCNT, tWT, tW);
    int ph = PH_[s], pw = ph;
    {
      int t1x = cdiv(pw, 16), t1y = cdiv(ph, 16);
      dim3 g1(t1x * t1y, 10, 8);
      k_conv1pool<<<g1, TPB, 0, stream>>>(ws + O_IMG, c1w, c1b, p1, ws + O_POOL,
                                          nh, nw, t1x);
    }
    int h2 = H2[s], w2 = h2;
    {
      int t2x = cdiv(w2, 64), t2y = cdiv(h2, 16);
      dim3 g2(t2x * t2y, 2, 8);
      k_conv3x3c8<<<g2, TPB, 0, stream>>>(ws + O_POOL, c2w, c2b, p2, ws + O_C2,
                                          10, 16, ph, pw, t2x);
    }
    int h3 = H3[s], w3 = h3;
    {
      int t3x = cdiv(w3, 64), t3y = cdiv(h3, 16);
      dim3 g3(t3x * t3y, 4, 8);
      k_conv3x3c8<<<g3, TPB, 0, stream>>>(ws + O_C2, c3w, c3b, p3, ws + O_C1,
                                          16, 32, h2, w2, t3x);
    }
    long cells = (long)8 * h3 * w3;
    k_head<<<cdiv(cells, TPB), TPB, 0, stream>>>(ws + O_C1, w41, b41, w42, b42,
                                                 ws + O_REG, keysA, h3, w3);
    int n = (int)cells;
    u64* src = keysA; u64* dst = keysB;
    while (n > 2048) {
      int blocks = cdiv(n, 2048);
      k_topk<<<blocks, TPB, 0, stream>>>(src, n, dst, 512);
      n = blocks * 512;
      u64* tmp = src; src = dst; dst = tmp;
    }
    k_topk<<<1, TPB, 0, stream>>>(src, n, selk + (long)s * 512, 512);
    k_gather<<<2, TPB, 0, stream>>>(selk + (long)s * 512, ws + O_REG,
                                    boxes + (long)s * 512 * 12, h3, w3, (float)scl[s]);
  }

  // ---------------- small scales 2..10: batched job pipeline ----------------
  {
    const int nj = NSMALL;
    int hOff[NSMALL], imgOff[NSMALL], poolOff[NSMALL], c2Off[NSMALL], c3Off[NSMALL];
    int kOff[NSMALL], cells[NSMALL];
    {
      int ch = 0, ci = 0, cp = 0, c2 = 0, c3 = 0, ck = 0;
      for (int q = 0; q < nj; ++q) {
        int s = q + 2;
        int nh = NH[s], ph = PH_[s], h2 = H2[s], h3 = H3[s];
        hOff[q] = ch;   ch += 24 * 768 * nh;
        imgOff[q] = ci; ci += 24 * nh * nh;
        poolOff[q] = cp; cp += 80 * ph * ph;
        c2Off[q] = c2;  c2 += 128 * h2 * h2;
        c3Off[q] = c3;  c3 += 256 * h3 * h3;
        kOff[q] = ck;   cells[q] = 8 * h3 * h3; ck += cells[q];
      }
    }
    // H pass (one image read for all 9 scales)
    {
      HallP P; P.nj = nj; int cw = 0;
      for (int q = 0; q < nj; ++q) {
        int s = q + 2;
        P.nw[q] = NH[s]; P.hOff[q] = hOff[q];
        P.oxB[q] = OXB[s]; P.T[q] = TT[s]; P.wOff[q] = WOFF[s];
        P.cumW[q] = cw; cw += 3 * NH[s];
      }
      P.cumW[nj] = cw;
      dim3 gh(768, 8, 1);
      k_resizeH_all<<<gh, TPB, 0, stream>>>(images, ws + O_C1, tX0, tCNT, tWT, tW, P);
    }
    // V pass
    {
      VallP P; P.nj = nj; int ce = 0;
      for (int q = 0; q < nj; ++q) {
        int s = q + 2;
        P.nh[q] = NH[s]; P.nw[q] = NH[s];
        P.hOff[q] = hOff[q]; P.imgOff[q] = imgOff[q];
        P.oxB[q] = OXB[s]; P.T[q] = TT[s]; P.wOff[q] = WOFF[s];
        P.cumE[q] = ce; ce += 24 * NH[s] * NH[s];
      }
      P.cumE[nj] = ce;
      k_resizeV_all<<<cdiv(ce, TPB), TPB, 0, stream>>>(ws + O_C1, ws + O_IMG,
                                                       tX0, tCNT, tWT, tW, P);
    }
    // conv1+pool
    {
      C1P P; P.nj = nj; int ct = 0;
      for (int q = 0; q < nj; ++q) {
        int s = q + 2;
        P.nh[q] = NH[s]; P.nw[q] = NH[s];
        P.imgOff[q] = imgOff[q]; P.poolOff[q] = poolOff[q];
        int t1x = cdiv(PH_[s], 16);
        P.t1x[q] = t1x;
        P.cumT[q] = ct; ct += t1x * t1x;
      }
      P.cumT[nj] = ct;
      dim3 g(ct, 10, 8);
      k_conv1pool_job<<<g, TPB, 0, stream>>>(ws + O_IMG, c1w, c1b, p1, ws + O_POOL, P);
    }
    // conv2
    {
      CvP P; P.nj = nj; int ct = 0;
      for (int q = 0; q < nj; ++q) {
        int s = q + 2;
        P.H[q] = PH_[s]; P.W[q] = PH_[s];
        P.inOff[q] = poolOff[q]; P.outOff[q] = c2Off[q];
        int tx = cdiv(H2[s], 64), ty = cdiv(H2[s], 16);
        P.tx[q] = tx;
        P.cumT[q] = ct; ct += tx * ty;
      }
      P.cumT[nj] = ct;
      dim3 g(ct, 2, 8);
      k_conv3x3c8_job<<<g, TPB, 0, stream>>>(ws + O_POOL, c2w, c2b, p2, ws + O_C2,
                                             10, 16, P);
    }
    // conv3
    {
      CvP P; P.nj = nj; int ct = 0;
      for (int q = 0; q < nj; ++q) {
        int s = q + 2;
        P.H[q] = H2[s]; P.W[q] = H2[s];
        P.inOff[q] = c2Off[q]; P.outOff[q] = c3Off[q];
        int tx = cdiv(H3[s], 64), ty = cdiv(H3[s], 16);
        P.tx[q] = tx;
        P.cumT[q] = ct; ct += tx * ty;
      }
      P.cumT[nj] = ct;
      dim3 g(ct, 4, 8);
      k_conv3x3c8_job<<<g, TPB, 0, stream>>>(ws + O_C2, c3w, c3b, p3, ws + O_C1,
                                             16, 32, P);
    }
    // heads
    {
      HdP P; P.nj = nj; int cc = 0;
      for (int q = 0; q < nj; ++q) {
        int s = q + 2;
        P.h3[q] = H3[s]; P.w3[q] = H3[s];
        P.c3Off[q] = c3Off[q]; P.kOff[q] = kOff[q];
        P.cumC[q] = cc; cc += cells[q];
      }
      P.cumC[nj] = cc;
      k_head_job<<<cdiv(cc, TPB), TPB, 0, stream>>>(ws + O_C1, w41, b41, w42, b42,
                                                    ws + O_REG, keysA, P);
    }
    // batched top-512 tournament
    {
      int bOff[NSMALL];
      {
        int c = 0;
        for (int q = 0; q < nj; ++q) { bOff[q] = c; c += 512 * cdiv(cells[q], 2048); }
      }
      long nCur[NSMALL]; int par[NSMALL];
      for (int q = 0; q < nj; ++q) { nCur[q] = cells[q]; par[q] = 0; }
      while (true) {
        TkP P; P.nj = 0; int cum = 0; int act[NSMALL];
        for (int q = 0; q < nj; ++q) {
          if (nCur[q] > 2048) {
            int r = P.nj++;
            act[r] = q;
            int blocks = cdiv(nCur[q], 2048);
            P.srcSel[r] = par[q];
            P.srcOff[r] = par[q] ? bOff[q] : kOff[q];
            P.dstOff[r] = par[q] ? kOff[q] : bOff[q];
            P.n[r] = (int)nCur[q];
            P.cumB[r] = cum; cum += blocks;
          }
        }
        P.cumB[P.nj] = cum;
        if (P.nj == 0) break;
        k_topk_job<<<cum, TPB, 0, stream>>>(keysA, keysB, P);
        for (int r = 0; r < P.nj; ++r) {
          int q = act[r];
          nCur[q] = 512L * cdiv(nCur[q], 2048);
          par[q] ^= 1;
        }
      }
      TkFP F; F.nj = nj;
      for (int q = 0; q < nj; ++q) {
        F.srcSel[q] = par[q];
        F.srcOff[q] = par[q] ? bOff[q] : kOff[q];
        F.n[q] = (int)nCur[q];
      }
      k_topk_fin<<<nj, TPB, 0, stream>>>(keysA, keysB, selk, F);
    }
    // batched gather
    {
      GtP P; P.nj = nj;
      for (int q = 0; q < nj; ++q) {
        int s = q + 2;
        P.h3[q] = H3[s]; P.w3[q] = H3[s]; P.scalef[q] = (float)scl[s]; P.kOff[q] = kOff[q];
      }
      k_gather_job<<<2 * nj, TPB, 0, stream>>>(selk, ws + O_REG, boxes, P);
    }
  }

  // ---------------- per-scale NMS + final stage ----------------
  k_nms<<<nsc, TPB, 0, stream>>>(boxes, 512, 0.5f);

  int total = nsc * 512;
  k_finalkeys<<<cdiv(8192, TPB), TPB, 0, stream>>>(boxes, fkeys, total, 8192);
  k_topk<<<4, TPB, 0, stream>>>(fkeys, 8192, keysB, 1024);
  k_topk<<<2, TPB, 0, stream>>>(keysB, 4096, keysA, 1024);
  k_topk<<<1, TPB, 0, stream>>>(keysA, 2048, fsel, 1024);
  k_gatherfinal<<<4, TPB, 0, stream>>>(fsel, boxes, self);
  k_nms<<<1, TPB, 0, stream>>>(self, 1024, 0.7f);
  k_refine<<<4, TPB, 0, stream>>>(self, (float*)d_out, 1024);
}

// Round 8
// 1951.512 us; speedup vs baseline: 1.0237x; 1.0237x over previous
//
#include <hip/hip_runtime.h>
#include <stdint.h>

typedef unsigned long long u64;
typedef unsigned int u32;

#define TPB 256
#define NSMALL 9   // scales 2..10 batched
#define NSC 11

__device__ __forceinline__ int findJob(const int* cum, int nj, int v) {
  int j = 0;
  while (j + 1 < nj && v >= cum[j + 1]) ++j;
  return j;
}

// ---------------- resize weight tables (per scale, per output position) -----
// tW layout: TRANSPOSED [k][ox]: tW[wOff + k*nh + ox]  (coalesced lane reads)
struct MkP { int ns; int nw[NSC]; float invs[NSC], ks[NSC];
             int oxB[NSC], T[NSC], wOff[NSC]; };

__global__ void k_mkweights(int* __restrict__ tX0, int* __restrict__ tCNT,
                            float* __restrict__ tWT, float* __restrict__ tW, MkP P) {
  const int s = blockIdx.x;
  const int nw = P.nw[s];
  const float invs = P.invs[s], ks = P.ks[s];
  const int T = P.T[s];
  for (int ox = threadIdx.x; ox < nw; ox += TPB) {
    float sx = ((float)ox + 0.5f) * invs - 0.5f;
    int x0 = (int)ceilf(sx - ks); if (x0 < 0) x0 = 0;
    int x1 = (int)floorf(sx + ks); if (x1 > 767) x1 = 767;
    float wt = 0.f;
    float* wv = tW + P.wOff[s];
    for (int j = x0; j <= x1; ++j) {
      float w = fmaxf(0.f, 1.f - fabsf(sx - (float)j) / ks);
      wt += w;
      wv[(j - x0) * nw + ox] = w;
    }
    for (int k = x1 - x0 + 1; k < T; ++k) wv[k * nw + ox] = 0.f;
    int g = P.oxB[s] + ox;
    tX0[g] = x0; tCNT[g] = x1 - x0 + 1; tWT[g] = wt;
  }
}

// ---------------- per-scale resize kernels (big scales 0,1) -----------------
__global__ void k_resizeHrow(const float* __restrict__ img, float* __restrict__ tmp,
                             int nw, int oxB, int wOff,
                             const int* __restrict__ tX0, const int* __restrict__ tCNT,
                             const float* __restrict__ tWT, const float* __restrict__ tW) {
  __shared__ float row[3][769];
  const int y = blockIdx.x, b = blockIdx.y;
  const float* src = img + ((long)b * 768 + y) * 768 * 3;
  for (int t = threadIdx.x; t < 2304; t += TPB) {
    int x = t / 3, c = t - 3 * x;
    row[c][x] = src[t];
  }
  __syncthreads();
  const int total = 3 * nw;
  for (int t = threadIdx.x; t < total; t += TPB) {
    int ox = t % nw, c = t / nw;
    int g = oxB + ox;
    int x0 = tX0[g], cnt = tCNT[g];
    float wt = tWT[g];
    const float* wv = tW + wOff + ox;
    float acc = 0.f;
    for (int k = 0; k < cnt; ++k) acc += row[c][x0 + k] * wv[(long)k * nw];
    tmp[(((long)b * 3 + c) * 768 + y) * nw + ox] = acc / wt;
  }
}

__global__ void k_resizeV(const float* __restrict__ tmp, float* __restrict__ out,
                          int nh, int nw, int oxB, int wOff,
                          const int* __restrict__ tX0, const int* __restrict__ tCNT,
                          const float* __restrict__ tWT, const float* __restrict__ tW) {
  long idx = (long)blockIdx.x * blockDim.x + threadIdx.x;
  long total = (long)8 * 3 * nh * nw;
  if (idx >= total) return;
  int ox = (int)(idx % nw); long t = idx / nw;
  int oy = (int)(t % nh); t /= nh;
  int c = (int)(t % 3); int b = (int)(t / 3);
  int g = oxB + oy;
  int y0 = tX0[g], cnt = tCNT[g];
  float wt = tWT[g];
  const float* wv = tW + wOff + oy;   // broadcast across lanes (same oy)
  const float* col = tmp + ((long)(b * 3 + c) * 768) * nw + ox;
  float acc = 0.f;
  for (int k = 0; k < cnt; ++k) acc += col[(long)(y0 + k) * nw] * wv[(long)k * nh];
  out[(((long)b * 3 + c) * nh + oy) * nw + ox] = (acc / wt - 127.5f) * 0.0078125f;
}

// ---------------- batched resize, scales 2..10 ------------------------------
struct HallP { int nj; int nw[NSMALL]; int hOff[NSMALL]; int cumW[NSMALL + 1];
               int oxB[NSMALL], wOff[NSMALL]; };

__global__ void k_resizeH_all(const float* __restrict__ img, float* __restrict__ base,
                              const int* __restrict__ tX0, const int* __restrict__ tCNT,
                              const float* __restrict__ tWT, const float* __restrict__ tW,
                              HallP P) {
  __shared__ float row[3][769];
  const int y = blockIdx.x, b = blockIdx.y;
  const float* src = img + ((long)b * 768 + y) * 768 * 3;
  for (int t = threadIdx.x; t < 2304; t += TPB) {
    int x = t / 3, c = t - 3 * x;
    row[c][x] = src[t];
  }
  __syncthreads();
  const int total = P.cumW[P.nj];
  for (int t = threadIdx.x; t < total; t += TPB) {
    int j = findJob(P.cumW, P.nj, t);
    int local = t - P.cumW[j];
    int nw = P.nw[j];
    int ox = local % nw, c = local / nw;
    int g = P.oxB[j] + ox;
    int x0 = tX0[g], cnt = tCNT[g];
    float wt = tWT[g];
    const float* wv = tW + P.wOff[j] + ox;
    float acc = 0.f;
    for (int k = 0; k < cnt; ++k) acc += row[c][x0 + k] * wv[(long)k * nw];
    base[P.hOff[j] + (((long)b * 3 + c) * 768 + y) * nw + ox] = acc / wt;
  }
}

struct VallP { int nj; int nh[NSMALL], nw[NSMALL];
               int hOff[NSMALL], imgOff[NSMALL]; int cumE[NSMALL + 1];
               int oxB[NSMALL], wOff[NSMALL]; };

__global__ void k_resizeV_all(const float* __restrict__ base, float* __restrict__ img,
                              const int* __restrict__ tX0, const int* __restrict__ tCNT,
                              const float* __restrict__ tWT, const float* __restrict__ tW,
                              VallP P) {
  int gid = blockIdx.x * TPB + threadIdx.x;
  if (gid >= P.cumE[P.nj]) return;
  int j = findJob(P.cumE, P.nj, gid);
  int local = gid - P.cumE[j];
  int nh = P.nh[j], nw = P.nw[j];
  int ox = local % nw; int t = local / nw;
  int oy = t % nh; t /= nh;
  int c = t % 3; int b = t / 3;
  int g = P.oxB[j] + oy;
  int y0 = tX0[g], cnt = tCNT[g];
  float wt = tWT[g];
  const float* wv = tW + P.wOff[j] + oy;
  const float* col = base + P.hOff[j] + ((long)(b * 3 + c) * 768) * nw + ox;
  float acc = 0.f;
  for (int k = 0; k < cnt; ++k) acc += col[(long)(y0 + k) * nw] * wv[(long)k * nh];
  img[P.imgOff[j] + (((long)b * 3 + c) * nh + oy) * nw + ox] =
      (acc / wt - 127.5f) * 0.0078125f;
}

// ---------------- fused conv1 + PReLU + 2x2 ceil-maxpool --------------------
__device__ __forceinline__ void conv1pool_body(
    const float* in, const float* w, const float* bias, const float* pr,
    float* out, int H, int W, int co, int b, int px, int py) {
  const int h1 = H - 2, w1 = W - 2;
  const int PH = (h1 + 1) >> 1, PW = (w1 + 1) >> 1;
  if (px >= PW || py >= PH) return;
  const int x0 = px * 2, y0 = py * 2;
  float a00 = 0.f, a01 = 0.f, a10 = 0.f, a11 = 0.f;
  const float* wp = w + (long)co * 27;
  const long HW = (long)H * W;
  const float* pp = in + ((long)b * 3 * H + y0) * W + x0;
  for (int ci = 0; ci < 3; ++ci, pp += HW) {
    const float* r = pp;
    float r00 = r[0], r01 = r[1], r02 = r[2], r03 = r[3]; r += W;
    float r10 = r[0], r11 = r[1], r12 = r[2], r13 = r[3]; r += W;
    float r20 = r[0], r21 = r[1], r22 = r[2], r23 = r[3]; r += W;
    float r30 = r[0], r31 = r[1], r32 = r[2], r33 = r[3];
    const float* wc = wp + ci * 9;
    float w0 = wc[0], w1_ = wc[1], w2 = wc[2];
    float w3 = wc[3], w4 = wc[4], w5 = wc[5];
    float w6 = wc[6], w7 = wc[7], w8 = wc[8];
    a00 += r00 * w0 + r01 * w1_ + r02 * w2;
    a00 += r10 * w3 + r11 * w4 + r12 * w5;
    a00 += r20 * w6 + r21 * w7 + r22 * w8;
    a01 += r01 * w0 + r02 * w1_ + r03 * w2;
    a01 += r11 * w3 + r12 * w4 + r13 * w5;
    a01 += r21 * w6 + r22 * w7 + r23 * w8;
    a10 += r10 * w0 + r11 * w1_ + r12 * w2;
    a10 += r20 * w3 + r21 * w4 + r22 * w5;
    a10 += r30 * w6 + r31 * w7 + r32 * w8;
    a11 += r11 * w0 + r12 * w1_ + r13 * w2;
    a11 += r21 * w3 + r22 * w4 + r23 * w5;
    a11 += r31 * w6 + r32 * w7 + r33 * w8;
  }
  const float bb = bias[co], al = pr[co];
  const bool vx = (x0 + 1 < w1), vy = (y0 + 1 < h1);
  float v = a00 + bb; v = v > 0.f ? v : al * v;
  float m = v;
  if (vx) { v = a01 + bb; v = v > 0.f ? v : al * v; m = fmaxf(m, v); }
  if (vy) { v = a10 + bb; v = v > 0.f ? v : al * v; m = fmaxf(m, v); }
  if (vx && vy) { v = a11 + bb; v = v > 0.f ? v : al * v; m = fmaxf(m, v); }
  out[(((long)b * 10 + co) * PH + py) * PW + px] = m;
}

__global__ void k_conv1pool(const float* __restrict__ in, const float* __restrict__ w,
                            const float* __restrict__ bias, const float* __restrict__ pr,
                            float* __restrict__ out, int H, int W, int tilesX) {
  const int tX = blockIdx.x % tilesX, tY = blockIdx.x / tilesX;
  conv1pool_body(in, w, bias, pr, out, H, W, blockIdx.y, blockIdx.z,
                 tX * 16 + (threadIdx.x & 15), tY * 16 + (threadIdx.x >> 4));
}

struct C1P { int nj; int nh[NSMALL], nw[NSMALL]; int imgOff[NSMALL], poolOff[NSMALL];
             int t1x[NSMALL]; int cumT[NSMALL + 1]; };

__global__ void k_conv1pool_job(const float* __restrict__ imgb, const float* __restrict__ w,
                                const float* __restrict__ bias, const float* __restrict__ pr,
                                float* __restrict__ poolb, C1P P) {
  int j = findJob(P.cumT, P.nj, blockIdx.x);
  int local = blockIdx.x - P.cumT[j];
  int t1x = P.t1x[j];
  int tX = local % t1x, tY = local / t1x;
  conv1pool_body(imgb + P.imgOff[j], w, bias, pr, poolb + P.poolOff[j],
                 P.nh[j], P.nw[j], blockIdx.y, blockIdx.z,
                 tX * 16 + (threadIdx.x & 15), tY * 16 + (threadIdx.x >> 4));
}

// ---------------- co-blocked tiled 3x3 conv + PReLU -------------------------
__device__ __forceinline__ void conv3x3c8_body(
    const float* in, const float* w, const float* bias, const float* pr,
    float* out, int Cin, int Cout, int H, int W, int cog, int b, int x0, int y) {
  const int OH = H - 2, OW = W - 2;
  if (y >= OH || x0 >= OW) return;
  float acc[8][4];
#pragma unroll
  for (int k = 0; k < 8; ++k) { acc[k][0] = 0.f; acc[k][1] = 0.f; acc[k][2] = 0.f; acc[k][3] = 0.f; }
  const float* wp = w + (long)cog * Cin * 9;
  const long HW = (long)H * W;
  const float* pp = in + ((long)b * Cin * H + y) * W + x0;
  for (int ci = 0; ci < Cin; ++ci, pp += HW) {
    const float* r = pp;
    float q00 = r[0], q01 = r[1], q02 = r[2], q03 = r[3], q04 = r[4], q05 = r[5]; r += W;
    float q10 = r[0], q11 = r[1], q12 = r[2], q13 = r[3], q14 = r[4], q15 = r[5]; r += W;
    float q20 = r[0], q21 = r[1], q22 = r[2], q23 = r[3], q24 = r[4], q25 = r[5];
#pragma unroll
    for (int k = 0; k < 8; ++k) {
      const float* wc = wp + ((long)k * Cin + ci) * 9;
      float w0 = wc[0], w1 = wc[1], w2 = wc[2];
      float w3 = wc[3], w4 = wc[4], w5 = wc[5];
      float w6 = wc[6], w7 = wc[7], w8 = wc[8];
      acc[k][0] += q00 * w0 + q01 * w1 + q02 * w2;
      acc[k][1] += q01 * w0 + q02 * w1 + q03 * w2;
      acc[k][2] += q02 * w0 + q03 * w1 + q04 * w2;
      acc[k][3] += q03 * w0 + q04 * w1 + q05 * w2;
      acc[k][0] += q10 * w3 + q11 * w4 + q12 * w5;
      acc[k][1] += q11 * w3 + q12 * w4 + q13 * w5;
      acc[k][2] += q12 * w3 + q13 * w4 + q14 * w5;
      acc[k][3] += q13 * w3 + q14 * w4 + q15 * w5;
      acc[k][0] += q20 * w6 + q21 * w7 + q22 * w8;
      acc[k][1] += q21 * w6 + q22 * w7 + q23 * w8;
      acc[k][2] += q22 * w6 + q23 * w7 + q24 * w8;
      acc[k][3] += q23 * w6 + q24 * w7 + q25 * w8;
    }
  }
  const int rem = OW - x0;
#pragma unroll
  for (int k = 0; k < 8; ++k) {
    const int co = cog + k;
    const float bb = bias[co], al = pr[co];
    float* op = out + (((long)b * Cout + co) * OH + y) * OW + x0;
    float v0 = acc[k][0] + bb; v0 = v0 > 0.f ? v0 : al * v0;
    op[0] = v0;
    if (rem > 1) { float v = acc[k][1] + bb; v = v > 0.f ? v : al * v; op[1] = v; }
    if (rem > 2) { float v = acc[k][2] + bb; v = v > 0.f ? v : al * v; op[2] = v; }
    if (rem > 3) { float v = acc[k][3] + bb; v = v > 0.f ? v : al * v; op[3] = v; }
  }
}

__global__ void k_conv3x3c8(const float* __restrict__ in, const float* __restrict__ w,
                            const float* __restrict__ bias, const float* __restrict__ pr,
                            float* __restrict__ out, int Cin, int Cout, int H, int W,
                            int tilesX) {
  const int tX = blockIdx.x % tilesX, tY = blockIdx.x / tilesX;
  conv3x3c8_body(in, w, bias, pr, out, Cin, Cout, H, W, blockIdx.y * 8, blockIdx.z,
                 tX * 64 + (threadIdx.x & 15) * 4, tY * 16 + (threadIdx.x >> 4));
}

struct CvP { int nj; int H[NSMALL], W[NSMALL]; int inOff[NSMALL], outOff[NSMALL];
             int tx[NSMALL]; int cumT[NSMALL + 1]; };

__global__ void k_conv3x3c8_job(const float* __restrict__ inb, const float* __restrict__ w,
                                const float* __restrict__ bias, const float* __restrict__ pr,
                                float* __restrict__ outb, int Cin, int Cout, CvP P) {
  int j = findJob(P.cumT, P.nj, blockIdx.x);
  int local = blockIdx.x - P.cumT[j];
  int tx0 = P.tx[j];
  int tX = local % tx0, tY = local / tx0;
  conv3x3c8_body(inb + P.inOff[j], w, bias, pr, outb + P.outOff[j], Cin, Cout,
                 P.H[j], P.W[j], blockIdx.y * 8, blockIdx.z,
                 tX * 64 + (threadIdx.x & 15) * 4, tY * 16 + (threadIdx.x >> 4));
}

// ---------------- 1x1 heads -------------------------------------------------
__device__ __forceinline__ void head_body(const float* x3, const float* w41,
                                          const float* b41, const float* w42,
                                          const float* b42, float* reg, u64* keys,
                                          int plane, long idx) {
  int b = (int)(idx / plane); int rem = (int)(idx % plane);
  const float* p = x3 + (long)b * 32 * plane + rem;
  float l0 = 0.f, l1 = 0.f, r0 = 0.f, r1 = 0.f, r2 = 0.f, r3 = 0.f;
  for (int c = 0; c < 32; ++c) {
    float v = p[(long)c * plane];
    l0 += v * w41[c];      l1 += v * w41[32 + c];
    r0 += v * w42[c];      r1 += v * w42[32 + c];
    r2 += v * w42[64 + c]; r3 += v * w42[96 + c];
  }
  l0 += b41[0]; l1 += b41[1];
  r0 += b42[0]; r1 += b42[1]; r2 += b42[2]; r3 += b42[3];
  float mx = fmaxf(l0, l1);
  float e0 = expf(l0 - mx), e1 = expf(l1 - mx);
  float s = e1 / (e0 + e1);
  reg[idx * 4 + 0] = r0; reg[idx * 4 + 1] = r1;
  reg[idx * 4 + 2] = r2; reg[idx * 4 + 3] = r3;
  u32 ic = 0xFFFFFFFFu - (u32)idx;
  u64 k = (s >= 0.6f) ? ((((u64)__float_as_uint(s)) << 32) | ic) : (u64)ic;
  keys[idx] = k;
}

__global__ void k_head(const float* __restrict__ x3, const float* __restrict__ w41,
                       const float* __restrict__ b41, const float* __restrict__ w42,
                       const float* __restrict__ b42, float* __restrict__ reg,
                       u64* __restrict__ keys, int H, int W) {
  long plane = (long)H * W;
  long idx = (long)blockIdx.x * blockDim.x + threadIdx.x;
  if (idx >= 8 * plane) return;
  head_body(x3, w41, b41, w42, b42, reg, keys, (int)plane, idx);
}

struct HdP { int nj; int h3[NSMALL], w3[NSMALL]; int c3Off[NSMALL], kOff[NSMALL];
             int cumC[NSMALL + 1]; };

__global__ void k_head_job(const float* __restrict__ c3b, const float* __restrict__ w41,
                           const float* __restrict__ b41, const float* __restrict__ w42,
                           const float* __restrict__ b42, float* __restrict__ regb,
                           u64* __restrict__ keysb, HdP P) {
  int gid = blockIdx.x * TPB + threadIdx.x;
  if (gid >= P.cumC[P.nj]) return;
  int j = findJob(P.cumC, P.nj, gid);
  int idx = gid - P.cumC[j];
  head_body(c3b + P.c3Off[j], w41, b41, w42, b42,
            regb + 4L * P.kOff[j], keysb + P.kOff[j], P.h3[j] * P.w3[j], idx);
}

// ---------------- bitonic top-K ---------------------------------------------
__device__ __forceinline__ void bitonic2048(u64* s) {
  for (int k = 2; k <= 2048; k <<= 1) {
    for (int j = k >> 1; j > 0; j >>= 1) {
      for (int i = threadIdx.x; i < 2048; i += TPB) {
        int ixj = i ^ j;
        if (ixj > i) {
          u64 a = s[i], b = s[ixj];
          bool desc = ((i & k) == 0);
          if (desc ? (a < b) : (a > b)) { s[i] = b; s[ixj] = a; }
        }
      }
      __syncthreads();
    }
  }
}

__global__ void k_topk(const u64* __restrict__ in, int n, u64* __restrict__ out, int K) {
  __shared__ u64 s[2048];
  int base = blockIdx.x * 2048;
  for (int t = threadIdx.x; t < 2048; t += TPB) {
    int gi = base + t;
    s[t] = (gi < n) ? in[gi] : 0ULL;
  }
  __syncthreads();
  bitonic2048(s);
  for (int t = threadIdx.x; t < K; t += TPB)
    out[(long)blockIdx.x * K + t] = s[t];
}

struct TkP { int nj; int srcSel[NSMALL]; int srcOff[NSMALL]; int n[NSMALL];
             int dstOff[NSMALL]; int cumB[NSMALL + 1]; };

__global__ void k_topk_job(u64* __restrict__ A, u64* __restrict__ B, TkP P) {
  __shared__ u64 s[2048];
  int j = findJob(P.cumB, P.nj, blockIdx.x);
  int lb = blockIdx.x - P.cumB[j];
  const u64* src = (P.srcSel[j] ? B : A) + P.srcOff[j];
  u64* dst = (P.srcSel[j] ? A : B) + P.dstOff[j];
  int n = P.n[j];
  int base = lb * 2048;
  for (int t = threadIdx.x; t < 2048; t += TPB) {
    int gi = base + t;
    s[t] = (gi < n) ? src[gi] : 0ULL;
  }
  __syncthreads();
  bitonic2048(s);
  for (int t = threadIdx.x; t < 512; t += TPB)
    dst[(long)lb * 512 + t] = s[t];
}

struct TkFP { int nj; int srcSel[NSMALL]; int srcOff[NSMALL]; int n[NSMALL]; };

__global__ void k_topk_fin(const u64* __restrict__ A, const u64* __restrict__ B,
                           u64* __restrict__ selk, TkFP P) {
  __shared__ u64 s[2048];
  int j = blockIdx.x;
  const u64* src = (P.srcSel[j] ? B : A) + P.srcOff[j];
  int n = P.n[j];
  for (int t = threadIdx.x; t < 2048; t += TPB)
    s[t] = (t < n) ? src[t] : 0ULL;
  __syncthreads();
  bitonic2048(s);
  for (int t = threadIdx.x; t < 512; t += TPB)
    selk[(long)(j + 2) * 512 + t] = s[t];
}

// ---------------- gather box rows -------------------------------------------
__device__ __forceinline__ void gather_body(const u64* keys, const float* reg,
                                            float* boxes, int h, int w, float scalef,
                                            int i) {
  float* bx = boxes + (long)i * 12;
  u64 key = keys[i];
  if ((key >> 32) == 0ULL) {
    for (int q = 0; q < 12; ++q) bx[q] = 0.f;
    return;
  }
  u32 cell = 0xFFFFFFFFu - (u32)(key & 0xFFFFFFFFu);
  int x = (int)(cell % (u32)w); u32 t2 = cell / (u32)w;
  int y = (int)(t2 % (u32)h); int b = (int)(t2 / (u32)h);
  float fx = (float)x, fy = (float)y;
  bx[0] = floorf((2.f * fx + 1.f) / scalef);
  bx[1] = floorf((2.f * fy + 1.f) / scalef);
  bx[2] = floorf((2.f * fx + 12.f) / scalef);
  bx[3] = floorf((2.f * fy + 12.f) / scalef);
  bx[4] = __uint_as_float((u32)(key >> 32));
  bx[5] = reg[(long)cell * 4 + 0];
  bx[6] = reg[(long)cell * 4 + 1];
  bx[7] = reg[(long)cell * 4 + 2];
  bx[8] = reg[(long)cell * 4 + 3];
  bx[9] = (float)b;
  bx[10] = 1.f;
  bx[11] = 0.f;
}

__global__ void k_gather(const u64* __restrict__ keys, const float* __restrict__ reg,
                         float* __restrict__ boxes, int h, int w, float scalef) {
  int i = blockIdx.x * blockDim.x + threadIdx.x;
  if (i >= 512) return;
  gather_body(keys, reg, boxes, h, w, scalef, i);
}

struct GtP { int nj; int h3[NSMALL], w3[NSMALL]; float scalef[NSMALL]; int kOff[NSMALL]; };

__global__ void k_gather_job(const u64* __restrict__ selk, const float* __restrict__ regb,
                             float* __restrict__ boxes, GtP P) {
  int j = blockIdx.x >> 1;
  int i = ((blockIdx.x & 1) << 8) + threadIdx.x;
  gather_body(selk + (long)(j + 2) * 512, regb + 4L * P.kOff[j],
              boxes + (long)(j + 2) * 512 * 12, P.h3[j], P.w3[j], P.scalef[j], i);
}

// ---------------- greedy NMS ------------------------------------------------
__global__ void k_nms(float* __restrict__ boxes, int per, float thr) {
  __shared__ float sx1[1024], sy1[1024], sx2[1024], sy2[1024], sar[1024];
  __shared__ unsigned char kp[1024];
  __shared__ int snv;
  float* bs = boxes + (long)blockIdx.x * per * 12;
  int N = per;
  if (threadIdx.x == 0) snv = 0;
  __syncthreads();
  for (int i = threadIdx.x; i < N; i += blockDim.x) {
    const float* b = bs + (long)i * 12;
    float off = b[9] * 100000.0f;
    float a0 = b[0] + off, a1 = b[1] + off, a2 = b[2] + off, a3 = b[3] + off;
    sx1[i] = a0; sy1[i] = a1; sx2[i] = a2; sy2[i] = a3;
    sar[i] = fmaxf(a2 - a0, 0.f) * fmaxf(a3 - a1, 0.f);
    bool v = (b[10] != 0.f);
    kp[i] = v;
    if (v) atomicMax(&snv, i + 1);
  }
  __syncthreads();
  int nv = snv;
  for (int i = 0; i < nv; ++i) {
    if (kp[i]) {
      float xi1 = sx1[i], yi1 = sy1[i], xi2 = sx2[i], yi2 = sy2[i], ai = sar[i];
      for (int j = threadIdx.x; j < nv; j += blockDim.x) {
        if (j > i && kp[j]) {
          float iw = fmaxf(fminf(xi2, sx2[j]) - fmaxf(xi1, sx1[j]), 0.f);
          float ih = fmaxf(fminf(yi2, sy2[j]) - fmaxf(yi1, sy1[j]), 0.f);
          float inter = iw * ih;
          float iou = inter / (ai + sar[j] - inter + 1e-9f);
          if (iou > thr) kp[j] = 0;
        }
      }
    }
    __syncthreads();
  }
  for (int i = threadIdx.x; i < N; i += blockDim.x)
    bs[(long)i * 12 + 11] = kp[i] ? 1.f : 0.f;
}

// ---------------- final stage ------------------------------------------------
__global__ void k_finalkeys(const float* __restrict__ boxes, u64* __restrict__ keys,
                            int total, int padded) {
  int i = blockIdx.x * blockDim.x + threadIdx.x;
  if (i >= padded) return;
  u64 k = 0ULL;
  if (i < total) {
    const float* b = boxes + (long)i * 12;
    u32 ic = 0xFFFFFFFFu - (u32)i;
    k = (b[11] != 0.f) ? ((((u64)__float_as_uint(b[4])) << 32) | ic) : (u64)ic;
  }
  keys[i] = k;
}

__global__ void k_gatherfinal(const u64* __restrict__ keys, const float* __restrict__ boxes,
                              float* __restrict__ sel) {
  int i = blockIdx.x * blockDim.x + threadIdx.x;
  if (i >= 1024) return;
  u64 key = keys[i];
  float* o = sel + (long)i * 12;
  if ((key >> 32) == 0ULL) {
    for (int q = 0; q < 12; ++q) o[q] = 0.f;
    return;
  }
  u32 bi = 0xFFFFFFFFu - (u32)(key & 0xFFFFFFFFu);
  const float* b = boxes + (long)bi * 12;
  for (int q = 0; q < 12; ++q) o[q] = b[q];
  o[10] = 1.f;
  o[11] = 0.f;
}

__global__ void k_refine(const float* __restrict__ sel, float* __restrict__ out, int N) {
  int i = blockIdx.x * blockDim.x + threadIdx.x;
  if (i >= N) return;
  const float* b = sel + (long)i * 12;
  float keep = b[11];
  float x1 = b[0], y1 = b[1], x2 = b[2], y2 = b[3], sc = b[4];
  float rw = x2 - x1, rh = y2 - y1;
  float o0 = x1 + b[5] * rw;
  float o1 = y1 + b[6] * rh;
  float o2 = x2 + b[7] * rw;
  float o3 = y2 + b[8] * rh;
  float hh = o3 - o1, ww = o2 - o0;
  float l = fmaxf(hh, ww);
  float nx1 = o0 + ww * 0.5f - l * 0.5f;
  float ny1 = o1 + hh * 0.5f - l * 0.5f;
  out[(long)i * 5 + 0] = nx1 * keep;
  out[(long)i * 5 + 1] = ny1 * keep;
  out[(long)i * 5 + 2] = (nx1 + l) * keep;
  out[(long)i * 5 + 3] = (ny1 + l) * keep;
  out[(long)i * 5 + 4] = sc * keep;
}

extern "C" void kernel_launch(void* const* d_in, const int* in_sizes, int n_in,
                              void* d_out, int out_size, void* d_ws, size_t ws_size,
                              hipStream_t stream) {
  (void)in_sizes; (void)n_in; (void)out_size; (void)ws_size;
  const float* images = (const float*)d_in[0];
  const float* c1w = (const float*)d_in[1];
  const float* c1b = (const float*)d_in[2];
  const float* p1  = (const float*)d_in[3];
  const float* c2w = (const float*)d_in[4];
  const float* c2b = (const float*)d_in[5];
  const float* p2  = (const float*)d_in[6];
  const float* c3w = (const float*)d_in[7];
  const float* c3b = (const float*)d_in[8];
  const float* p3  = (const float*)d_in[9];
  const float* w41 = (const float*)d_in[10];
  const float* b41 = (const float*)d_in[11];
  const float* w42 = (const float*)d_in[12];
  const float* b42 = (const float*)d_in[13];
  float* ws = (float*)d_ws;

  const long O_IMG  = 0;
  const long O_C1   = 5101008;
  const long O_POOL = O_C1 + 16854496;
  const long O_C2   = O_POOL + 4232000;
  const long O_REG  = O_C2 + 6653952;
  const long O_KA   = O_REG + 1634432;
  const long O_KB   = O_KA + 817216;
  const long O_SEL  = O_KB + 204800;
  const long O_BOX  = O_SEL + 11264;
  const long O_FK   = O_BOX + 67584;
  const long O_FS   = O_FK + 16384;
  const long O_SF   = O_FS + 2048;
  // weight tables live in the dead tail of O_C1 (max O_C1 usage = 14.08M floats)
  const long O_TBL  = O_C1 + 16000000;

  u64* keysA = (u64*)(ws + O_KA);
  u64* keysB = (u64*)(ws + O_KB);
  u64* selk  = (u64*)(ws + O_SEL);
  u64* fkeys = (u64*)(ws + O_FK);
  u64* fsel  = (u64*)(ws + O_FS);
  float* boxes = ws + O_BOX;
  float* self  = ws + O_SF;
  int*   tX0  = (int*)(ws + O_TBL);
  int*   tCNT = (int*)(ws + O_TBL + 4096);
  float* tWT  = ws + O_TBL + 8192;
  float* tW   = ws + O_TBL + 12288;

  double scl[16]; int nsc = 0;
  {
    double m = 12.0 / 20.0;
    double ml = 768.0 * m;
    double si = m;
    while (ml >= 12.0) { scl[nsc++] = si; si *= 0.709; ml *= 0.709; }
  }

  auto cdiv = [](long a, long b) { return (int)((a + b - 1) / b); };

  // per-scale dims + table geometry
  int NH[NSC], PH_[NSC], H2[NSC], H3[NSC], OXB[NSC], TT[NSC], WOFF[NSC];
  float INV[NSC], KSF[NSC];
  {
    int oxb = 0, woff = 0;
    for (int s = 0; s < nsc; ++s) {
      int nh = (int)(768.0 * scl[s] + 1.0);
      NH[s] = nh;
      PH_[s] = ((nh - 2) + 1) / 2;
      H2[s] = PH_[s] - 2;
      H3[s] = H2[s] - 2;
      double inv = 1.0 / (((double)nh) / 768.0);
      INV[s] = (float)inv;
      KSF[s] = (float)(inv > 1.0 ? inv : 1.0);
      TT[s] = (int)(2.0f * KSF[s]) + 2;
      OXB[s] = oxb; oxb += nh;
      WOFF[s] = woff; woff += nh * TT[s];
    }
  }

  // build resize weight tables (once per launch)
  {
    MkP P; P.ns = nsc;
    for (int s = 0; s < nsc; ++s) {
      P.nw[s] = NH[s]; P.invs[s] = INV[s]; P.ks[s] = KSF[s];
      P.oxB[s] = OXB[s]; P.T[s] = TT[s]; P.wOff[s] = WOFF[s];
    }
    k_mkweights<<<nsc, TPB, 0, stream>>>(tX0, tCNT, tWT, tW, P);
  }

  // ---------------- big scales 0,1: per-scale chains ----------------
  for (int s = 0; s < 2; ++s) {
    int nh = NH[s], nw = nh;
    {
      dim3 gh(768, 8, 1);
      k_resizeHrow<<<gh, TPB, 0, stream>>>(images, ws + O_C1, nw,
                                           OXB[s], WOFF[s], tX0, tCNT, tWT, tW);
    }
    k_resizeV<<<cdiv((long)8 * 3 * nh * nw, TPB), TPB, 0, stream>>>(
        ws + O_C1, ws + O_IMG, nh, nw, OXB[s], WOFF[s], tX0, tCNT, tWT, tW);
    int ph = PH_[s], pw = ph;
    {
      int t1x = cdiv(pw, 16), t1y = cdiv(ph, 16);
      dim3 g1(t1x * t1y, 10, 8);
      k_conv1pool<<<g1, TPB, 0, stream>>>(ws + O_IMG, c1w, c1b, p1, ws + O_POOL,
                                          nh, nw, t1x);
    }
    int h2 = H2[s], w2 = h2;
    {
      int t2x = cdiv(w2, 64), t2y = cdiv(h2, 16);
      dim3 g2(t2x * t2y, 2, 8);
      k_conv3x3c8<<<g2, TPB, 0, stream>>>(ws + O_POOL, c2w, c2b, p2, ws + O_C2,
                                          10, 16, ph, pw, t2x);
    }
    int h3 = H3[s], w3 = h3;
    {
      int t3x = cdiv(w3, 64), t3y = cdiv(h3, 16);
      dim3 g3(t3x * t3y, 4, 8);
      k_conv3x3c8<<<g3, TPB, 0, stream>>>(ws + O_C2, c3w, c3b, p3, ws + O_C1,
                                          16, 32, h2, w2, t3x);
    }
    long cells = (long)8 * h3 * w3;
    k_head<<<cdiv(cells, TPB), TPB, 0, stream>>>(ws + O_C1, w41, b41, w42, b42,
                                                 ws + O_REG, keysA, h3, w3);
    int n = (int)cells;
    u64* src = keysA; u64* dst = keysB;
    while (n > 2048) {
      int blocks = cdiv(n, 2048);
      k_topk<<<blocks, TPB, 0, stream>>>(src, n, dst, 512);
      n = blocks * 512;
      u64* tmp = src; src = dst; dst = tmp;
    }
    k_topk<<<1, TPB, 0, stream>>>(src, n, selk + (long)s * 512, 512);
    k_gather<<<2, TPB, 0, stream>>>(selk + (long)s * 512, ws + O_REG,
                                    boxes + (long)s * 512 * 12, h3, w3, (float)scl[s]);
  }

  // ---------------- small scales 2..10: batched job pipeline ----------------
  {
    const int nj = NSMALL;
    int hOff[NSMALL], imgOff[NSMALL], poolOff[NSMALL], c2Off[NSMALL], c3Off[NSMALL];
    int kOff[NSMALL], cells[NSMALL];
    {
      int ch = 0, ci = 0, cp = 0, c2 = 0, c3 = 0, ck = 0;
      for (int q = 0; q < nj; ++q) {
        int s = q + 2;
        int nh = NH[s], ph = PH_[s], h2 = H2[s], h3 = H3[s];
        hOff[q] = ch;   ch += 24 * 768 * nh;
        imgOff[q] = ci; ci += 24 * nh * nh;
        poolOff[q] = cp; cp += 80 * ph * ph;
        c2Off[q] = c2;  c2 += 128 * h2 * h2;
        c3Off[q] = c3;  c3 += 256 * h3 * h3;
        kOff[q] = ck;   cells[q] = 8 * h3 * h3; ck += cells[q];
      }
    }
    // H pass (one image read for all 9 scales)
    {
      HallP P; P.nj = nj; int cw = 0;
      for (int q = 0; q < nj; ++q) {
        int s = q + 2;
        P.nw[q] = NH[s]; P.hOff[q] = hOff[q];
        P.oxB[q] = OXB[s]; P.wOff[q] = WOFF[s];
        P.cumW[q] = cw; cw += 3 * NH[s];
      }
      P.cumW[nj] = cw;
      dim3 gh(768, 8, 1);
      k_resizeH_all<<<gh, TPB, 0, stream>>>(images, ws + O_C1, tX0, tCNT, tWT, tW, P);
    }
    // V pass
    {
      VallP P; P.nj = nj; int ce = 0;
      for (int q = 0; q < nj; ++q) {
        int s = q + 2;
        P.nh[q] = NH[s]; P.nw[q] = NH[s];
        P.hOff[q] = hOff[q]; P.imgOff[q] = imgOff[q];
        P.oxB[q] = OXB[s]; P.wOff[q] = WOFF[s];
        P.cumE[q] = ce; ce += 24 * NH[s] * NH[s];
      }
      P.cumE[nj] = ce;
      k_resizeV_all<<<cdiv(ce, TPB), TPB, 0, stream>>>(ws + O_C1, ws + O_IMG,
                                                       tX0, tCNT, tWT, tW, P);
    }
    // conv1+pool
    {
      C1P P; P.nj = nj; int ct = 0;
      for (int q = 0; q < nj; ++q) {
        int s = q + 2;
        P.nh[q] = NH[s]; P.nw[q] = NH[s];
        P.imgOff[q] = imgOff[q]; P.poolOff[q] = poolOff[q];
        int t1x = cdiv(PH_[s], 16);
        P.t1x[q] = t1x;
        P.cumT[q] = ct; ct += t1x * t1x;
      }
      P.cumT[nj] = ct;
      dim3 g(ct, 10, 8);
      k_conv1pool_job<<<g, TPB, 0, stream>>>(ws + O_IMG, c1w, c1b, p1, ws + O_POOL, P);
    }
    // conv2
    {
      CvP P; P.nj = nj; int ct = 0;
      for (int q = 0; q < nj; ++q) {
        int s = q + 2;
        P.H[q] = PH_[s]; P.W[q] = PH_[s];
        P.inOff[q] = poolOff[q]; P.outOff[q] = c2Off[q];
        int tx = cdiv(H2[s], 64), ty = cdiv(H2[s], 16);
        P.tx[q] = tx;
        P.cumT[q] = ct; ct += tx * ty;
      }
      P.cumT[nj] = ct;
      dim3 g(ct, 2, 8);
      k_conv3x3c8_job<<<g, TPB, 0, stream>>>(ws + O_POOL, c2w, c2b, p2, ws + O_C2,
                                             10, 16, P);
    }
    // conv3
    {
      CvP P; P.nj = nj; int ct = 0;
      for (int q = 0; q < nj; ++q) {
        int s = q + 2;
        P.H[q] = H2[s]; P.W[q] = H2[s];
        P.inOff[q] = c2Off[q]; P.outOff[q] = c3Off[q];
        int tx = cdiv(H3[s], 64), ty = cdiv(H3[s], 16);
        P.tx[q] = tx;
        P.cumT[q] = ct; ct += tx * ty;
      }
      P.cumT[nj] = ct;
      dim3 g(ct, 4, 8);
      k_conv3x3c8_job<<<g, TPB, 0, stream>>>(ws + O_C2, c3w, c3b, p3, ws + O_C1,
                                             16, 32, P);
    }
    // heads
    {
      HdP P; P.nj = nj; int cc = 0;
      for (int q = 0; q < nj; ++q) {
        int s = q + 2;
        P.h3[q] = H3[s]; P.w3[q] = H3[s];
        P.c3Off[q] = c3Off[q]; P.kOff[q] = kOff[q];
        P.cumC[q] = cc; cc += cells[q];
      }
      P.cumC[nj] = cc;
      k_head_job<<<cdiv(cc, TPB), TPB, 0, stream>>>(ws + O_C1, w41, b41, w42, b42,
                                                    ws + O_REG, keysA, P);
    }
    // batched top-512 tournament
    {
      int bOff[NSMALL];
      {
        int c = 0;
        for (int q = 0; q < nj; ++q) { bOff[q] = c; c += 512 * cdiv(cells[q], 2048); }
      }
      long nCur[NSMALL]; int par[NSMALL];
      for (int q = 0; q < nj; ++q) { nCur[q] = cells[q]; par[q] = 0; }
      while (true) {
        TkP P; P.nj = 0; int cum = 0; int act[NSMALL];
        for (int q = 0; q < nj; ++q) {
          if (nCur[q] > 2048) {
            int r = P.nj++;
            act[r] = q;
            int blocks = cdiv(nCur[q], 2048);
            P.srcSel[r] = par[q];
            P.srcOff[r] = par[q] ? bOff[q] : kOff[q];
            P.dstOff[r] = par[q] ? kOff[q] : bOff[q];
            P.n[r] = (int)nCur[q];
            P.cumB[r] = cum; cum += blocks;
          }
        }
        P.cumB[P.nj] = cum;
        if (P.nj == 0) break;
        k_topk_job<<<cum, TPB, 0, stream>>>(keysA, keysB, P);
        for (int r = 0; r < P.nj; ++r) {
          int q = act[r];
          nCur[q] = 512L * cdiv(nCur[q], 2048);
          par[q] ^= 1;
        }
      }
      TkFP F; F.nj = nj;
      for (int q = 0; q < nj; ++q) {
        F.srcSel[q] = par[q];
        F.srcOff[q] = par[q] ? bOff[q] : kOff[q];
        F.n[q] = (int)nCur[q];
      }
      k_topk_fin<<<nj, TPB, 0, stream>>>(keysA, keysB, selk, F);
    }
    // batched gather
    {
      GtP P; P.nj = nj;
      for (int q = 0; q < nj; ++q) {
        int s = q + 2;
        P.h3[q] = H3[s]; P.w3[q] = H3[s]; P.scalef[q] = (float)scl[s]; P.kOff[q] = kOff[q];
      }
      k_gather_job<<<2 * nj, TPB, 0, stream>>>(selk, ws + O_REG, boxes, P);
    }
  }

  // ---------------- per-scale NMS + final stage ----------------
  k_nms<<<nsc, TPB, 0, stream>>>(boxes, 512, 0.5f);

  int total = nsc * 512;
  k_finalkeys<<<cdiv(8192, TPB), TPB, 0, stream>>>(boxes, fkeys, total, 8192);
  k_topk<<<4, TPB, 0, stream>>>(fkeys, 8192, keysB, 1024);
  k_topk<<<2, TPB, 0, stream>>>(keysB, 4096, keysA, 1024);
  k_topk<<<1, TPB, 0, stream>>>(keysA, 2048, fsel, 1024);
  k_gatherfinal<<<4, TPB, 0, stream>>>(fsel, boxes, self);
  k_nms<<<1, TPB, 0, stream>>>(self, 1024, 0.7f);
  k_refine<<<4, TPB, 0, stream>>>(self, (float*)d_out, 1024);
}

// Round 9
// 1615.183 us; speedup vs baseline: 1.2368x; 1.2082x over previous
//
#include <hip/hip_runtime.h>
#include <stdint.h>

typedef unsigned long long u64;
typedef unsigned int u32;

#define TPB 256
#define NJMAX 8    // max jobs per group (G1 has 7)
#define NSC 11

__device__ __forceinline__ int findJob(const int* cum, int nj, int v) {
  int j = 0;
  while (j + 1 < nj && v >= cum[j + 1]) ++j;
  return j;
}

// ---------------- resize weight tables (per scale, per output position) -----
// tW layout: TRANSPOSED [k][ox]: tW[wOff + k*nh + ox]  (coalesced lane reads)
struct MkP { int ns; int nw[NSC]; float invs[NSC], ks[NSC];
             int oxB[NSC], T[NSC], wOff[NSC]; };

__global__ void k_mkweights(int* __restrict__ tX0, int* __restrict__ tCNT,
                            float* __restrict__ tWT, float* __restrict__ tW, MkP P) {
  const int s = blockIdx.x;
  const int nw = P.nw[s];
  const float invs = P.invs[s], ks = P.ks[s];
  const int T = P.T[s];
  for (int ox = threadIdx.x; ox < nw; ox += TPB) {
    float sx = ((float)ox + 0.5f) * invs - 0.5f;
    int x0 = (int)ceilf(sx - ks); if (x0 < 0) x0 = 0;
    int x1 = (int)floorf(sx + ks); if (x1 > 767) x1 = 767;
    float wt = 0.f;
    float* wv = tW + P.wOff[s];
    for (int j = x0; j <= x1; ++j) {
      float w = fmaxf(0.f, 1.f - fabsf(sx - (float)j) / ks);
      wt += w;
      wv[(j - x0) * nw + ox] = w;
    }
    for (int k = x1 - x0 + 1; k < T; ++k) wv[k * nw + ox] = 0.f;
    int g = P.oxB[s] + ox;
    tX0[g] = x0; tCNT[g] = x1 - x0 + 1; tWT[g] = wt;
  }
}

// ---------------- batched resize (all scales via job groups) ----------------
struct HallP { int nj; int nw[NJMAX]; int hOff[NJMAX]; int cumW[NJMAX + 1];
               int oxB[NJMAX], wOff[NJMAX]; };

__global__ void k_resizeH_all(const float* __restrict__ img, float* __restrict__ base,
                              const int* __restrict__ tX0, const int* __restrict__ tCNT,
                              const float* __restrict__ tWT, const float* __restrict__ tW,
                              HallP P) {
  __shared__ float row[3][769];
  const int y = blockIdx.x, b = blockIdx.y;
  const float* src = img + ((long)b * 768 + y) * 768 * 3;
  for (int t = threadIdx.x; t < 2304; t += TPB) {
    int x = t / 3, c = t - 3 * x;
    row[c][x] = src[t];
  }
  __syncthreads();
  const int total = P.cumW[P.nj];
  for (int t = threadIdx.x; t < total; t += TPB) {
    int j = findJob(P.cumW, P.nj, t);
    int local = t - P.cumW[j];
    int nw = P.nw[j];
    int ox = local % nw, c = local / nw;
    int g = P.oxB[j] + ox;
    int x0 = tX0[g], cnt = tCNT[g];
    float wt = tWT[g];
    const float* wv = tW + P.wOff[j] + ox;
    float acc = 0.f;
    for (int k = 0; k < cnt; ++k) acc += row[c][x0 + k] * wv[(long)k * nw];
    base[P.hOff[j] + (((long)b * 3 + c) * 768 + y) * nw + ox] = acc / wt;
  }
}

struct VallP { int nj; int nh[NJMAX], nw[NJMAX];
               int hOff[NJMAX], imgOff[NJMAX]; int cumE[NJMAX + 1];
               int oxB[NJMAX], wOff[NJMAX]; };

__global__ void k_resizeV_all(const float* __restrict__ base, float* __restrict__ img,
                              const int* __restrict__ tX0, const int* __restrict__ tCNT,
                              const float* __restrict__ tWT, const float* __restrict__ tW,
                              VallP P) {
  int gid = blockIdx.x * TPB + threadIdx.x;
  if (gid >= P.cumE[P.nj]) return;
  int j = findJob(P.cumE, P.nj, gid);
  int local = gid - P.cumE[j];
  int nh = P.nh[j], nw = P.nw[j];
  int ox = local % nw; int t = local / nw;
  int oy = t % nh; t /= nh;
  int c = t % 3; int b = t / 3;
  int g = P.oxB[j] + oy;
  int y0 = tX0[g], cnt = tCNT[g];
  float wt = tWT[g];
  const float* wv = tW + P.wOff[j] + oy;   // broadcast across lanes (same oy)
  const float* col = base + P.hOff[j] + ((long)(b * 3 + c) * 768) * nw + ox;
  float acc = 0.f;
  for (int k = 0; k < cnt; ++k) acc += col[(long)(y0 + k) * nw] * wv[(long)k * nh];
  img[P.imgOff[j] + (((long)b * 3 + c) * nh + oy) * nw + ox] =
      (acc / wt - 127.5f) * 0.0078125f;
}

// ---------------- fused conv1 + PReLU + 2x2 ceil-maxpool --------------------
__device__ __forceinline__ void conv1pool_body(
    const float* in, const float* w, const float* bias, const float* pr,
    float* out, int H, int W, int co, int b, int px, int py) {
  const int h1 = H - 2, w1 = W - 2;
  const int PH = (h1 + 1) >> 1, PW = (w1 + 1) >> 1;
  if (px >= PW || py >= PH) return;
  const int x0 = px * 2, y0 = py * 2;
  float a00 = 0.f, a01 = 0.f, a10 = 0.f, a11 = 0.f;
  const float* wp = w + (long)co * 27;
  const long HW = (long)H * W;
  const float* pp = in + ((long)b * 3 * H + y0) * W + x0;
  for (int ci = 0; ci < 3; ++ci, pp += HW) {
    const float* r = pp;
    float r00 = r[0], r01 = r[1], r02 = r[2], r03 = r[3]; r += W;
    float r10 = r[0], r11 = r[1], r12 = r[2], r13 = r[3]; r += W;
    float r20 = r[0], r21 = r[1], r22 = r[2], r23 = r[3]; r += W;
    float r30 = r[0], r31 = r[1], r32 = r[2], r33 = r[3];
    const float* wc = wp + ci * 9;
    float w0 = wc[0], w1_ = wc[1], w2 = wc[2];
    float w3 = wc[3], w4 = wc[4], w5 = wc[5];
    float w6 = wc[6], w7 = wc[7], w8 = wc[8];
    a00 += r00 * w0 + r01 * w1_ + r02 * w2;
    a00 += r10 * w3 + r11 * w4 + r12 * w5;
    a00 += r20 * w6 + r21 * w7 + r22 * w8;
    a01 += r01 * w0 + r02 * w1_ + r03 * w2;
    a01 += r11 * w3 + r12 * w4 + r13 * w5;
    a01 += r21 * w6 + r22 * w7 + r23 * w8;
    a10 += r10 * w0 + r11 * w1_ + r12 * w2;
    a10 += r20 * w3 + r21 * w4 + r22 * w5;
    a10 += r30 * w6 + r31 * w7 + r32 * w8;
    a11 += r11 * w0 + r12 * w1_ + r13 * w2;
    a11 += r21 * w3 + r22 * w4 + r23 * w5;
    a11 += r31 * w6 + r32 * w7 + r33 * w8;
  }
  const float bb = bias[co], al = pr[co];
  const bool vx = (x0 + 1 < w1), vy = (y0 + 1 < h1);
  float v = a00 + bb; v = v > 0.f ? v : al * v;
  float m = v;
  if (vx) { v = a01 + bb; v = v > 0.f ? v : al * v; m = fmaxf(m, v); }
  if (vy) { v = a10 + bb; v = v > 0.f ? v : al * v; m = fmaxf(m, v); }
  if (vx && vy) { v = a11 + bb; v = v > 0.f ? v : al * v; m = fmaxf(m, v); }
  out[(((long)b * 10 + co) * PH + py) * PW + px] = m;
}

struct C1P { int nj; int nh[NJMAX]; int imgOff[NJMAX], poolOff[NJMAX];
             int t1x[NJMAX]; int cumT[NJMAX + 1]; };

__global__ void k_conv1pool_job(const float* __restrict__ imgb, const float* __restrict__ w,
                                const float* __restrict__ bias, const float* __restrict__ pr,
                                float* __restrict__ poolb, C1P P) {
  int j = findJob(P.cumT, P.nj, blockIdx.x);
  int local = blockIdx.x - P.cumT[j];
  int t1x = P.t1x[j];
  int tX = local % t1x, tY = local / t1x;
  conv1pool_body(imgb + P.imgOff[j], w, bias, pr, poolb + P.poolOff[j],
                 P.nh[j], P.nh[j], blockIdx.y, blockIdx.z,
                 tX * 16 + (threadIdx.x & 15), tY * 16 + (threadIdx.x >> 4));
}

// ---------------- co-blocked tiled 3x3 conv + PReLU -------------------------
__device__ __forceinline__ void conv3x3c8_body(
    const float* in, const float* w, const float* bias, const float* pr,
    float* out, int Cin, int Cout, int H, int W, int cog, int b, int x0, int y) {
  const int OH = H - 2, OW = W - 2;
  if (y >= OH || x0 >= OW) return;
  float acc[8][4];
#pragma unroll
  for (int k = 0; k < 8; ++k) { acc[k][0] = 0.f; acc[k][1] = 0.f; acc[k][2] = 0.f; acc[k][3] = 0.f; }
  const float* wp = w + (long)cog * Cin * 9;
  const long HW = (long)H * W;
  const float* pp = in + ((long)b * Cin * H + y) * W + x0;
  for (int ci = 0; ci < Cin; ++ci, pp += HW) {
    const float* r = pp;
    float q00 = r[0], q01 = r[1], q02 = r[2], q03 = r[3], q04 = r[4], q05 = r[5]; r += W;
    float q10 = r[0], q11 = r[1], q12 = r[2], q13 = r[3], q14 = r[4], q15 = r[5]; r += W;
    float q20 = r[0], q21 = r[1], q22 = r[2], q23 = r[3], q24 = r[4], q25 = r[5];
#pragma unroll
    for (int k = 0; k < 8; ++k) {
      const float* wc = wp + ((long)k * Cin + ci) * 9;
      float w0 = wc[0], w1 = wc[1], w2 = wc[2];
      float w3 = wc[3], w4 = wc[4], w5 = wc[5];
      float w6 = wc[6], w7 = wc[7], w8 = wc[8];
      acc[k][0] += q00 * w0 + q01 * w1 + q02 * w2;
      acc[k][1] += q01 * w0 + q02 * w1 + q03 * w2;
      acc[k][2] += q02 * w0 + q03 * w1 + q04 * w2;
      acc[k][3] += q03 * w0 + q04 * w1 + q05 * w2;
      acc[k][0] += q10 * w3 + q11 * w4 + q12 * w5;
      acc[k][1] += q11 * w3 + q12 * w4 + q13 * w5;
      acc[k][2] += q12 * w3 + q13 * w4 + q14 * w5;
      acc[k][3] += q13 * w3 + q14 * w4 + q15 * w5;
      acc[k][0] += q20 * w6 + q21 * w7 + q22 * w8;
      acc[k][1] += q21 * w6 + q22 * w7 + q23 * w8;
      acc[k][2] += q22 * w6 + q23 * w7 + q24 * w8;
      acc[k][3] += q23 * w6 + q24 * w7 + q25 * w8;
    }
  }
  const int rem = OW - x0;
#pragma unroll
  for (int k = 0; k < 8; ++k) {
    const int co = cog + k;
    const float bb = bias[co], al = pr[co];
    float* op = out + (((long)b * Cout + co) * OH + y) * OW + x0;
    float v0 = acc[k][0] + bb; v0 = v0 > 0.f ? v0 : al * v0;
    op[0] = v0;
    if (rem > 1) { float v = acc[k][1] + bb; v = v > 0.f ? v : al * v; op[1] = v; }
    if (rem > 2) { float v = acc[k][2] + bb; v = v > 0.f ? v : al * v; op[2] = v; }
    if (rem > 3) { float v = acc[k][3] + bb; v = v > 0.f ? v : al * v; op[3] = v; }
  }
}

struct CvP { int nj; int H[NJMAX]; int inOff[NJMAX], outOff[NJMAX];
             int tx[NJMAX]; int cumT[NJMAX + 1]; };

__global__ void k_conv3x3c8_job(const float* __restrict__ inb, const float* __restrict__ w,
                                const float* __restrict__ bias, const float* __restrict__ pr,
                                float* __restrict__ outb, int Cin, int Cout, CvP P) {
  int j = findJob(P.cumT, P.nj, blockIdx.x);
  int local = blockIdx.x - P.cumT[j];
  int tx0 = P.tx[j];
  int tX = local % tx0, tY = local / tx0;
  conv3x3c8_body(inb + P.inOff[j], w, bias, pr, outb + P.outOff[j], Cin, Cout,
                 P.H[j], P.H[j], blockIdx.y * 8, blockIdx.z,
                 tX * 64 + (threadIdx.x & 15) * 4, tY * 16 + (threadIdx.x >> 4));
}

// ---------------- 1x1 heads -------------------------------------------------
__device__ __forceinline__ void head_body(const float* x3, const float* w41,
                                          const float* b41, const float* w42,
                                          const float* b42, float* reg, u64* keys,
                                          int plane, long idx) {
  int b = (int)(idx / plane); int rem = (int)(idx % plane);
  const float* p = x3 + (long)b * 32 * plane + rem;
  float l0 = 0.f, l1 = 0.f, r0 = 0.f, r1 = 0.f, r2 = 0.f, r3 = 0.f;
  for (int c = 0; c < 32; ++c) {
    float v = p[(long)c * plane];
    l0 += v * w41[c];      l1 += v * w41[32 + c];
    r0 += v * w42[c];      r1 += v * w42[32 + c];
    r2 += v * w42[64 + c]; r3 += v * w42[96 + c];
  }
  l0 += b41[0]; l1 += b41[1];
  r0 += b42[0]; r1 += b42[1]; r2 += b42[2]; r3 += b42[3];
  float mx = fmaxf(l0, l1);
  float e0 = expf(l0 - mx), e1 = expf(l1 - mx);
  float s = e1 / (e0 + e1);
  reg[idx * 4 + 0] = r0; reg[idx * 4 + 1] = r1;
  reg[idx * 4 + 2] = r2; reg[idx * 4 + 3] = r3;
  u32 ic = 0xFFFFFFFFu - (u32)idx;
  u64 k = (s >= 0.6f) ? ((((u64)__float_as_uint(s)) << 32) | ic) : (u64)ic;
  keys[idx] = k;
}

struct HdP { int nj; int h3[NJMAX]; int c3Off[NJMAX], kOff[NJMAX];
             int cumC[NJMAX + 1]; };

__global__ void k_head_job(const float* __restrict__ c3b, const float* __restrict__ w41,
                           const float* __restrict__ b41, const float* __restrict__ w42,
                           const float* __restrict__ b42, float* __restrict__ regb,
                           u64* __restrict__ keysb, HdP P) {
  int gid = blockIdx.x * TPB + threadIdx.x;
  if (gid >= P.cumC[P.nj]) return;
  int j = findJob(P.cumC, P.nj, gid);
  int idx = gid - P.cumC[j];
  head_body(c3b + P.c3Off[j], w41, b41, w42, b42,
            regb + 4L * P.kOff[j], keysb + P.kOff[j], P.h3[j] * P.h3[j], idx);
}

// ---------------- bitonic top-K ---------------------------------------------
__device__ __forceinline__ void bitonic2048(u64* s) {
  for (int k = 2; k <= 2048; k <<= 1) {
    for (int j = k >> 1; j > 0; j >>= 1) {
      for (int i = threadIdx.x; i < 2048; i += TPB) {
        int ixj = i ^ j;
        if (ixj > i) {
          u64 a = s[i], b = s[ixj];
          bool desc = ((i & k) == 0);
          if (desc ? (a < b) : (a > b)) { s[i] = b; s[ixj] = a; }
        }
      }
      __syncthreads();
    }
  }
}

__global__ void k_topk(const u64* __restrict__ in, int n, u64* __restrict__ out, int K) {
  __shared__ u64 s[2048];
  int base = blockIdx.x * 2048;
  for (int t = threadIdx.x; t < 2048; t += TPB) {
    int gi = base + t;
    s[t] = (gi < n) ? in[gi] : 0ULL;
  }
  __syncthreads();
  bitonic2048(s);
  for (int t = threadIdx.x; t < K; t += TPB)
    out[(long)blockIdx.x * K + t] = s[t];
}

struct TkP { int nj; int srcSel[NJMAX]; int srcOff[NJMAX]; int n[NJMAX];
             int dstOff[NJMAX]; int cumB[NJMAX + 1]; };

__global__ void k_topk_job(u64* __restrict__ A, u64* __restrict__ B, TkP P) {
  __shared__ u64 s[2048];
  int j = findJob(P.cumB, P.nj, blockIdx.x);
  int lb = blockIdx.x - P.cumB[j];
  const u64* src = (P.srcSel[j] ? B : A) + P.srcOff[j];
  u64* dst = (P.srcSel[j] ? A : B) + P.dstOff[j];
  int n = P.n[j];
  int base = lb * 2048;
  for (int t = threadIdx.x; t < 2048; t += TPB) {
    int gi = base + t;
    s[t] = (gi < n) ? src[gi] : 0ULL;
  }
  __syncthreads();
  bitonic2048(s);
  for (int t = threadIdx.x; t < 512; t += TPB)
    dst[(long)lb * 512 + t] = s[t];
}

struct TkFP { int nj; int srcSel[NJMAX]; int srcOff[NJMAX]; int n[NJMAX]; int sIdx[NJMAX]; };

__global__ void k_topk_fin(const u64* __restrict__ A, const u64* __restrict__ B,
                           u64* __restrict__ selk, TkFP P) {
  __shared__ u64 s[2048];
  int j = blockIdx.x;
  const u64* src = (P.srcSel[j] ? B : A) + P.srcOff[j];
  int n = P.n[j];
  for (int t = threadIdx.x; t < 2048; t += TPB)
    s[t] = (t < n) ? src[t] : 0ULL;
  __syncthreads();
  bitonic2048(s);
  for (int t = threadIdx.x; t < 512; t += TPB)
    selk[(long)P.sIdx[j] * 512 + t] = s[t];
}

// ---------------- gather box rows -------------------------------------------
__device__ __forceinline__ void gather_body(const u64* keys, const float* reg,
                                            float* boxes, int h, int w, float scalef,
                                            int i) {
  float* bx = boxes + (long)i * 12;
  u64 key = keys[i];
  if ((key >> 32) == 0ULL) {
    for (int q = 0; q < 12; ++q) bx[q] = 0.f;
    return;
  }
  u32 cell = 0xFFFFFFFFu - (u32)(key & 0xFFFFFFFFu);
  int x = (int)(cell % (u32)w); u32 t2 = cell / (u32)w;
  int y = (int)(t2 % (u32)h); int b = (int)(t2 / (u32)h);
  float fx = (float)x, fy = (float)y;
  bx[0] = floorf((2.f * fx + 1.f) / scalef);
  bx[1] = floorf((2.f * fy + 1.f) / scalef);
  bx[2] = floorf((2.f * fx + 12.f) / scalef);
  bx[3] = floorf((2.f * fy + 12.f) / scalef);
  bx[4] = __uint_as_float((u32)(key >> 32));
  bx[5] = reg[(long)cell * 4 + 0];
  bx[6] = reg[(long)cell * 4 + 1];
  bx[7] = reg[(long)cell * 4 + 2];
  bx[8] = reg[(long)cell * 4 + 3];
  bx[9] = (float)b;
  bx[10] = 1.f;
  bx[11] = 0.f;
}

struct GtP { int nj; int h3[NJMAX]; float scalef[NJMAX]; int kOff[NJMAX]; int sIdx[NJMAX]; };

__global__ void k_gather_job(const u64* __restrict__ selk, const float* __restrict__ regb,
                             float* __restrict__ boxes, GtP P) {
  int j = blockIdx.x >> 1;
  int i = ((blockIdx.x & 1) << 8) + threadIdx.x;
  gather_body(selk + (long)P.sIdx[j] * 512, regb + 4L * P.kOff[j],
              boxes + (long)P.sIdx[j] * 512 * 12, P.h3[j], P.h3[j], P.scalef[j], i);
}

// ---------------- greedy NMS ------------------------------------------------
__global__ void k_nms(float* __restrict__ boxes, int per, float thr) {
  __shared__ float sx1[1024], sy1[1024], sx2[1024], sy2[1024], sar[1024];
  __shared__ unsigned char kp[1024];
  __shared__ int snv;
  float* bs = boxes + (long)blockIdx.x * per * 12;
  int N = per;
  if (threadIdx.x == 0) snv = 0;
  __syncthreads();
  for (int i = threadIdx.x; i < N; i += blockDim.x) {
    const float* b = bs + (long)i * 12;
    float off = b[9] * 100000.0f;
    float a0 = b[0] + off, a1 = b[1] + off, a2 = b[2] + off, a3 = b[3] + off;
    sx1[i] = a0; sy1[i] = a1; sx2[i] = a2; sy2[i] = a3;
    sar[i] = fmaxf(a2 - a0, 0.f) * fmaxf(a3 - a1, 0.f);
    bool v = (b[10] != 0.f);
    kp[i] = v;
    if (v) atomicMax(&snv, i + 1);
  }
  __syncthreads();
  int nv = snv;
  for (int i = 0; i < nv; ++i) {
    if (kp[i]) {
      float xi1 = sx1[i], yi1 = sy1[i], xi2 = sx2[i], yi2 = sy2[i], ai = sar[i];
      for (int j = threadIdx.x; j < nv; j += blockDim.x) {
        if (j > i && kp[j]) {
          float iw = fmaxf(fminf(xi2, sx2[j]) - fmaxf(xi1, sx1[j]), 0.f);
          float ih = fmaxf(fminf(yi2, sy2[j]) - fmaxf(yi1, sy1[j]), 0.f);
          float inter = iw * ih;
          float iou = inter / (ai + sar[j] - inter + 1e-9f);
          if (iou > thr) kp[j] = 0;
        }
      }
    }
    __syncthreads();
  }
  for (int i = threadIdx.x; i < N; i += blockDim.x)
    bs[(long)i * 12 + 11] = kp[i] ? 1.f : 0.f;
}

// ---------------- final stage ------------------------------------------------
__global__ void k_finalkeys(const float* __restrict__ boxes, u64* __restrict__ keys,
                            int total, int padded) {
  int i = blockIdx.x * blockDim.x + threadIdx.x;
  if (i >= padded) return;
  u64 k = 0ULL;
  if (i < total) {
    const float* b = boxes + (long)i * 12;
    u32 ic = 0xFFFFFFFFu - (u32)i;
    k = (b[11] != 0.f) ? ((((u64)__float_as_uint(b[4])) << 32) | ic) : (u64)ic;
  }
  keys[i] = k;
}

__global__ void k_gatherfinal(const u64* __restrict__ keys, const float* __restrict__ boxes,
                              float* __restrict__ sel) {
  int i = blockIdx.x * blockDim.x + threadIdx.x;
  if (i >= 1024) return;
  u64 key = keys[i];
  float* o = sel + (long)i * 12;
  if ((key >> 32) == 0ULL) {
    for (int q = 0; q < 12; ++q) o[q] = 0.f;
    return;
  }
  u32 bi = 0xFFFFFFFFu - (u32)(key & 0xFFFFFFFFu);
  const float* b = boxes + (long)bi * 12;
  for (int q = 0; q < 12; ++q) o[q] = b[q];
  o[10] = 1.f;
  o[11] = 0.f;
}

__global__ void k_refine(const float* __restrict__ sel, float* __restrict__ out, int N) {
  int i = blockIdx.x * blockDim.x + threadIdx.x;
  if (i >= N) return;
  const float* b = sel + (long)i * 12;
  float keep = b[11];
  float x1 = b[0], y1 = b[1], x2 = b[2], y2 = b[3], sc = b[4];
  float rw = x2 - x1, rh = y2 - y1;
  float o0 = x1 + b[5] * rw;
  float o1 = y1 + b[6] * rh;
  float o2 = x2 + b[7] * rw;
  float o3 = y2 + b[8] * rh;
  float hh = o3 - o1, ww = o2 - o0;
  float l = fmaxf(hh, ww);
  float nx1 = o0 + ww * 0.5f - l * 0.5f;
  float ny1 = o1 + hh * 0.5f - l * 0.5f;
  out[(long)i * 5 + 0] = nx1 * keep;
  out[(long)i * 5 + 1] = ny1 * keep;
  out[(long)i * 5 + 2] = (nx1 + l) * keep;
  out[(long)i * 5 + 3] = (ny1 + l) * keep;
  out[(long)i * 5 + 4] = sc * keep;
}

extern "C" void kernel_launch(void* const* d_in, const int* in_sizes, int n_in,
                              void* d_out, int out_size, void* d_ws, size_t ws_size,
                              hipStream_t stream) {
  (void)in_sizes; (void)n_in; (void)out_size; (void)ws_size;
  const float* images = (const float*)d_in[0];
  const float* c1w = (const float*)d_in[1];
  const float* c1b = (const float*)d_in[2];
  const float* p1  = (const float*)d_in[3];
  const float* c2w = (const float*)d_in[4];
  const float* c2b = (const float*)d_in[5];
  const float* p2  = (const float*)d_in[6];
  const float* c3w = (const float*)d_in[7];
  const float* c3b = (const float*)d_in[8];
  const float* p3  = (const float*)d_in[9];
  const float* w41 = (const float*)d_in[10];
  const float* b41 = (const float*)d_in[11];
  const float* w42 = (const float*)d_in[12];
  const float* b42 = (const float*)d_in[13];
  float* ws = (float*)d_ws;

  // ---- workspace layout (floats). Region A hosts htmp then (after V) c3. ----
  const long O_HT   = 0;                   // max(htmp G2 15,501,312; c3 13.7M)
  const long O_IMG  = 15501312;            // 5,429,312
  const long O_POOL = O_IMG + 5429312;     // 4,493,360
  const long O_C2   = O_POOL + 4493360;    // 7,013,248
  const long O_REG  = O_C2 + 7013248;      // 1,711,072
  const long O_KEYS = O_REG + 1711072;     // 855,536 (427,768 u64)
  const long O_SCR  = O_KEYS + 855536;     // 218,112 (109,056 u64)
  const long O_SEL  = O_SCR + 218112;      // 11*512 u64
  const long O_BOX  = O_SEL + 11264;       // 5632*12
  const long O_FK   = O_BOX + 67584;       // 8192 u64
  const long O_FS   = O_FK + 16384;        // 1024 u64
  const long O_SF   = O_FS + 2048;         // 1024*12
  const long O_TBL  = O_SF + 12288;        // tables (~32k)

  u64* keys  = (u64*)(ws + O_KEYS);
  u64* scr   = (u64*)(ws + O_SCR);
  u64* selk  = (u64*)(ws + O_SEL);
  u64* fkeys = (u64*)(ws + O_FK);
  u64* fsel  = (u64*)(ws + O_FS);
  float* boxes = ws + O_BOX;
  float* self  = ws + O_SF;
  int*   tX0  = (int*)(ws + O_TBL);
  int*   tCNT = (int*)(ws + O_TBL + 4096);
  float* tWT  = ws + O_TBL + 8192;
  float* tW   = ws + O_TBL + 12288;

  double scl[16]; int nsc = 0;
  {
    double m = 12.0 / 20.0;
    double ml = 768.0 * m;
    double si = m;
    while (ml >= 12.0) { scl[nsc++] = si; si *= 0.709; ml *= 0.709; }
  }

  auto cdiv = [](long a, long b) { return (int)((a + b - 1) / b); };

  // per-scale dims + table geometry
  int NH[NSC], PH_[NSC], H2[NSC], H3[NSC], OXB[NSC], TT[NSC], WOFF[NSC];
  float INV[NSC], KSF[NSC];
  {
    int oxb = 0, woff = 0;
    for (int s = 0; s < nsc; ++s) {
      int nh = (int)(768.0 * scl[s] + 1.0);
      NH[s] = nh;
      PH_[s] = ((nh - 2) + 1) / 2;
      H2[s] = PH_[s] - 2;
      H3[s] = H2[s] - 2;
      double inv = 1.0 / (((double)nh) / 768.0);
      INV[s] = (float)inv;
      KSF[s] = (float)(inv > 1.0 ? inv : 1.0);
      TT[s] = (int)(2.0f * KSF[s]) + 2;
      OXB[s] = oxb; oxb += nh;
      WOFF[s] = woff; woff += nh * TT[s];
    }
  }

  // build resize weight tables (once per launch)
  {
    MkP P; P.ns = nsc;
    for (int s = 0; s < nsc; ++s) {
      P.nw[s] = NH[s]; P.invs[s] = INV[s]; P.ks[s] = KSF[s];
      P.oxB[s] = OXB[s]; P.T[s] = TT[s]; P.wOff[s] = WOFF[s];
    }
    k_mkweights<<<nsc, TPB, 0, stream>>>(tX0, tCNT, tWT, tW, P);
  }

  // ---------------- unified job pipeline, two scale groups ----------------
  auto runGroup = [&](const int* gs, int nj) {
    int htmpOff[NJMAX], imgOff[NJMAX], poolOff[NJMAX], c2Off[NJMAX], c3Off[NJMAX];
    int kOff[NJMAX], cells[NJMAX];
    {
      long ch = 0, ci = 0, cp = 0, c2 = 0, c3 = 0, ck = 0;
      for (int q = 0; q < nj; ++q) {
        int s = gs[q];
        htmpOff[q] = (int)ch; ch += 24L * 768 * NH[s];
        imgOff[q]  = (int)ci; ci += 24L * NH[s] * NH[s];
        poolOff[q] = (int)cp; cp += 80L * PH_[s] * PH_[s];
        c2Off[q]   = (int)c2; c2 += 128L * H2[s] * H2[s];
        c3Off[q]   = (int)c3; c3 += 256L * H3[s] * H3[s];
        kOff[q]    = (int)ck; cells[q] = 8 * H3[s] * H3[s]; ck += cells[q];
      }
    }
    // H pass (one image read for the whole group)
    {
      HallP P; P.nj = nj; int cw = 0;
      for (int q = 0; q < nj; ++q) {
        int s = gs[q];
        P.nw[q] = NH[s]; P.hOff[q] = htmpOff[q];
        P.oxB[q] = OXB[s]; P.wOff[q] = WOFF[s];
        P.cumW[q] = cw; cw += 3 * NH[s];
      }
      P.cumW[nj] = cw;
      dim3 gh(768, 8, 1);
      k_resizeH_all<<<gh, TPB, 0, stream>>>(images, ws + O_HT, tX0, tCNT, tWT, tW, P);
    }
    // V pass
    {
      VallP P; P.nj = nj; int ce = 0;
      for (int q = 0; q < nj; ++q) {
        int s = gs[q];
        P.nh[q] = NH[s]; P.nw[q] = NH[s];
        P.hOff[q] = htmpOff[q]; P.imgOff[q] = imgOff[q];
        P.oxB[q] = OXB[s]; P.wOff[q] = WOFF[s];
        P.cumE[q] = ce; ce += 24 * NH[s] * NH[s];
      }
      P.cumE[nj] = ce;
      k_resizeV_all<<<cdiv(ce, TPB), TPB, 0, stream>>>(ws + O_HT, ws + O_IMG,
                                                       tX0, tCNT, tWT, tW, P);
    }
    // conv1+pool
    {
      C1P P; P.nj = nj; int ct = 0;
      for (int q = 0; q < nj; ++q) {
        int s = gs[q];
        P.nh[q] = NH[s];
        P.imgOff[q] = imgOff[q]; P.poolOff[q] = poolOff[q];
        int t1x = cdiv(PH_[s], 16);
        P.t1x[q] = t1x;
        P.cumT[q] = ct; ct += t1x * t1x;
      }
      P.cumT[nj] = ct;
      dim3 g(ct, 10, 8);
      k_conv1pool_job<<<g, TPB, 0, stream>>>(ws + O_IMG, c1w, c1b, p1, ws + O_POOL, P);
    }
    // conv2
    {
      CvP P; P.nj = nj; int ct = 0;
      for (int q = 0; q < nj; ++q) {
        int s = gs[q];
        P.H[q] = PH_[s];
        P.inOff[q] = poolOff[q]; P.outOff[q] = c2Off[q];
        int tx = cdiv(H2[s], 64), ty = cdiv(H2[s], 16);
        P.tx[q] = tx;
        P.cumT[q] = ct; ct += tx * ty;
      }
      P.cumT[nj] = ct;
      dim3 g(ct, 2, 8);
      k_conv3x3c8_job<<<g, TPB, 0, stream>>>(ws + O_POOL, c2w, c2b, p2, ws + O_C2,
                                             10, 16, P);
    }
    // conv3 (writes into region A; htmp is dead after V pass)
    {
      CvP P; P.nj = nj; int ct = 0;
      for (int q = 0; q < nj; ++q) {
        int s = gs[q];
        P.H[q] = H2[s];
        P.inOff[q] = c2Off[q]; P.outOff[q] = c3Off[q];
        int tx = cdiv(H3[s], 64), ty = cdiv(H3[s], 16);
        P.tx[q] = tx;
        P.cumT[q] = ct; ct += tx * ty;
      }
      P.cumT[nj] = ct;
      dim3 g(ct, 4, 8);
      k_conv3x3c8_job<<<g, TPB, 0, stream>>>(ws + O_C2, c3w, c3b, p3, ws + O_HT,
                                             16, 32, P);
    }
    // heads
    {
      HdP P; P.nj = nj; int cc = 0;
      for (int q = 0; q < nj; ++q) {
        int s = gs[q];
        P.h3[q] = H3[s];
        P.c3Off[q] = c3Off[q]; P.kOff[q] = kOff[q];
        P.cumC[q] = cc; cc += cells[q];
      }
      P.cumC[nj] = cc;
      k_head_job<<<cdiv(cc, TPB), TPB, 0, stream>>>(ws + O_HT, w41, b41, w42, b42,
                                                    ws + O_REG, keys, P);
    }
    // batched top-512 tournament
    {
      int bOff[NJMAX];
      {
        int c = 0;
        for (int q = 0; q < nj; ++q) { bOff[q] = c; c += 512 * cdiv(cells[q], 2048); }
      }
      long nCur[NJMAX]; int par[NJMAX];
      for (int q = 0; q < nj; ++q) { nCur[q] = cells[q]; par[q] = 0; }
      while (true) {
        TkP P; P.nj = 0; int cum = 0; int act[NJMAX];
        for (int q = 0; q < nj; ++q) {
          if (nCur[q] > 2048) {
            int r = P.nj++;
            act[r] = q;
            int blocks = cdiv(nCur[q], 2048);
            P.srcSel[r] = par[q];
            P.srcOff[r] = par[q] ? bOff[q] : kOff[q];
            P.dstOff[r] = par[q] ? kOff[q] : bOff[q];
            P.n[r] = (int)nCur[q];
            P.cumB[r] = cum; cum += blocks;
          }
        }
        P.cumB[P.nj] = cum;
        if (P.nj == 0) break;
        k_topk_job<<<cum, TPB, 0, stream>>>(keys, scr, P);
        for (int r = 0; r < P.nj; ++r) {
          int q = act[r];
          nCur[q] = 512L * cdiv(nCur[q], 2048);
          par[q] ^= 1;
        }
      }
      TkFP F; F.nj = nj;
      for (int q = 0; q < nj; ++q) {
        F.srcSel[q] = par[q];
        F.srcOff[q] = par[q] ? bOff[q] : kOff[q];
        F.n[q] = (int)nCur[q];
        F.sIdx[q] = gs[q];
      }
      k_topk_fin<<<nj, TPB, 0, stream>>>(keys, scr, selk, F);
    }
    // gather
    {
      GtP P; P.nj = nj;
      for (int q = 0; q < nj; ++q) {
        int s = gs[q];
        P.h3[q] = H3[s]; P.scalef[q] = (float)scl[s]; P.kOff[q] = kOff[q];
        P.sIdx[q] = s;
      }
      k_gather_job<<<2 * nj, TPB, 0, stream>>>(selk, ws + O_REG, boxes, P);
    }
  };

  const int G1[7] = {0, 5, 6, 7, 8, 9, 10};
  const int G2[4] = {1, 2, 3, 4};
  runGroup(G1, 7);
  runGroup(G2, 4);

  // ---------------- per-scale NMS + final stage ----------------
  k_nms<<<nsc, TPB, 0, stream>>>(boxes, 512, 0.5f);

  int total = nsc * 512;
  k_finalkeys<<<cdiv(8192, TPB), TPB, 0, stream>>>(boxes, fkeys, total, 8192);
  k_topk<<<4, TPB, 0, stream>>>(fkeys, 8192, scr, 1024);
  k_topk<<<2, TPB, 0, stream>>>(scr, 4096, keys, 1024);
  k_topk<<<1, TPB, 0, stream>>>(keys, 2048, fsel, 1024);
  k_gatherfinal<<<4, TPB, 0, stream>>>(fsel, boxes, self);
  k_nms<<<1, TPB, 0, stream>>>(self, 1024, 0.7f);
  k_refine<<<4, TPB, 0, stream>>>(self, (float*)d_out, 1024);
}

// Round 10
// 1583.097 us; speedup vs baseline: 1.2619x; 1.0203x over previous
//
#include <hip/hip_runtime.h>
#include <stdint.h>

typedef unsigned long long u64;
typedef unsigned int u32;

#define TPB 256
#define NJMAX 8    // max jobs per group (G1 has 7)
#define NSC 11
#define HDCAP 2560
#define VDCAP 20480

__device__ __forceinline__ int findJob(const int* cum, int nj, int v) {
  int j = 0;
  while (j + 1 < nj && v >= cum[j + 1]) ++j;
  return j;
}

// ---------------- resize weight tables (per scale, per output position) -----
// tW layout: TRANSPOSED [k][ox]: tW[wOff + k*nh + ox]  (coalesced lane reads)
struct MkP { int ns; int nw[NSC]; float invs[NSC], ks[NSC];
             int oxB[NSC], T[NSC], wOff[NSC]; };

__global__ void k_mkweights(int* __restrict__ tX0, int* __restrict__ tCNT,
                            float* __restrict__ tWT, float* __restrict__ tW, MkP P) {
  const int s = blockIdx.x;
  const int nw = P.nw[s];
  const float invs = P.invs[s], ks = P.ks[s];
  const int T = P.T[s];
  for (int ox = threadIdx.x; ox < nw; ox += TPB) {
    float sx = ((float)ox + 0.5f) * invs - 0.5f;
    int x0 = (int)ceilf(sx - ks); if (x0 < 0) x0 = 0;
    int x1 = (int)floorf(sx + ks); if (x1 > 767) x1 = 767;
    float wt = 0.f;
    float* wv = tW + P.wOff[s];
    for (int j = x0; j <= x1; ++j) {
      float w = fmaxf(0.f, 1.f - fabsf(sx - (float)j) / ks);
      wt += w;
      wv[(j - x0) * nw + ox] = w;
    }
    for (int k = x1 - x0 + 1; k < T; ++k) wv[k * nw + ox] = 0.f;
    int g = P.oxB[s] + ox;
    tX0[g] = x0; tCNT[g] = x1 - x0 + 1; tWT[g] = wt;
  }
}

// ---------------- descriptor builder (geometry-only, once per group) --------
struct DscP { int nj; int N[NJMAX]; int hOff[NJMAX], imgOff[NJMAX];
              int oxB[NJMAX], wOff[NJMAX];
              int cumW[NJMAX + 1], cumR[NJMAX + 1]; };

__global__ void k_mkdesc(int* __restrict__ hd, int* __restrict__ vd, DscP P) {
  int gid = blockIdx.x * TPB + threadIdx.x;
  int totW = P.cumW[P.nj], totR = P.cumR[P.nj];
  if (gid < totW) {
    int j = findJob(P.cumW, P.nj, gid);
    int local = gid - P.cumW[j];
    int N = P.N[j];
    int ox = local % N, c = local / N;
    hd[gid]             = P.hOff[j] + c * 768 * N + ox;   // A
    hd[HDCAP + gid]     = c * 769;                        // R (LDS row base)
    hd[2 * HDCAP + gid] = N;                              // stride
    hd[3 * HDCAP + gid] = P.oxB[j] + ox;                  // g
    hd[4 * HDCAP + gid] = P.wOff[j] + ox;                 // W
  }
  if (gid < totR) {
    int j = findJob(P.cumR, P.nj, gid);
    int local = gid - P.cumR[j];
    int N = P.N[j];
    int oy = local % N, q = local / N;   // q = b*3+c in 0..23
    vd[gid]             = P.hOff[j] + q * 768 * N;        // S (src col base)
    vd[VDCAP + gid]     = P.imgOff[j] + (q * N + oy) * N; // O (out row base)
    vd[2 * VDCAP + gid] = P.oxB[j] + oy;                  // g
    vd[3 * VDCAP + gid] = P.wOff[j] + oy;                 // W
    vd[4 * VDCAP + gid] = N;                              // stride
  }
}

// ---------------- H pass: descriptor-driven, row-resident -------------------
__global__ void k_resizeH_d(const float* __restrict__ img, float* __restrict__ base,
                            const int* __restrict__ tX0, const int* __restrict__ tCNT,
                            const float* __restrict__ tWT, const float* __restrict__ tW,
                            const int* __restrict__ hd, int total) {
  __shared__ float row[3][769];
  const int y = blockIdx.x, b = blockIdx.y;
  const float* src = img + ((long)b * 768 + y) * 768 * 3;
  for (int t = threadIdx.x; t < 2304; t += TPB) {
    int x = t / 3, c = t - 3 * x;
    row[c][x] = src[t];
  }
  __syncthreads();
  const float* rowF = &row[0][0];
  const long yb = (long)y + 2304L * b;
  for (int t = threadIdx.x; t < total; t += TPB) {
    int A = hd[t];
    int R = hd[HDCAP + t];
    int N = hd[2 * HDCAP + t];
    int g = hd[3 * HDCAP + t];
    int W = hd[4 * HDCAP + t];
    int x0 = tX0[g], cnt = tCNT[g];
    float wt = tWT[g];
    const float* wv = tW + W;
    float acc = 0.f;
    for (int k = 0; k < cnt; ++k) acc += rowF[R + x0 + k] * wv[(long)k * N];
    base[(long)A + (long)N * yb] = acc / wt;
  }
}

// ---------------- V pass: one 64-lane wave per output row -------------------
__global__ void k_resizeV_row(const float* __restrict__ basep, float* __restrict__ img,
                              const int* __restrict__ tX0, const int* __restrict__ tCNT,
                              const float* __restrict__ tWT, const float* __restrict__ tW,
                              const int* __restrict__ vd, int nRows) {
  int row = blockIdx.x * 4 + (threadIdx.x >> 6);
  if (row >= nRows) return;
  int lane = threadIdx.x & 63;
  int S = vd[row];
  int O = vd[VDCAP + row];
  int g = vd[2 * VDCAP + row];
  int W = vd[3 * VDCAP + row];
  int N = vd[4 * VDCAP + row];
  int y0 = tX0[g], cnt = tCNT[g];
  float wt = tWT[g];
  const float* wv = tW + W;
  const float* col0 = basep + S;
  for (int ox = lane; ox < N; ox += 64) {
    const float* col = col0 + ox;
    float acc = 0.f;
    for (int k = 0; k < cnt; ++k) acc += col[(long)(y0 + k) * N] * wv[(long)k * N];
    img[(long)O + ox] = (acc / wt - 127.5f) * 0.0078125f;
  }
}

// ---------------- fused conv1 + PReLU + 2x2 ceil-maxpool --------------------
__device__ __forceinline__ void conv1pool_body(
    const float* in, const float* w, const float* bias, const float* pr,
    float* out, int H, int W, int co, int b, int px, int py) {
  const int h1 = H - 2, w1 = W - 2;
  const int PH = (h1 + 1) >> 1, PW = (w1 + 1) >> 1;
  if (px >= PW || py >= PH) return;
  const int x0 = px * 2, y0 = py * 2;
  float a00 = 0.f, a01 = 0.f, a10 = 0.f, a11 = 0.f;
  const float* wp = w + (long)co * 27;
  const long HW = (long)H * W;
  const float* pp = in + ((long)b * 3 * H + y0) * W + x0;
  for (int ci = 0; ci < 3; ++ci, pp += HW) {
    const float* r = pp;
    float r00 = r[0], r01 = r[1], r02 = r[2], r03 = r[3]; r += W;
    float r10 = r[0], r11 = r[1], r12 = r[2], r13 = r[3]; r += W;
    float r20 = r[0], r21 = r[1], r22 = r[2], r23 = r[3]; r += W;
    float r30 = r[0], r31 = r[1], r32 = r[2], r33 = r[3];
    const float* wc = wp + ci * 9;
    float w0 = wc[0], w1_ = wc[1], w2 = wc[2];
    float w3 = wc[3], w4 = wc[4], w5 = wc[5];
    float w6 = wc[6], w7 = wc[7], w8 = wc[8];
    a00 += r00 * w0 + r01 * w1_ + r02 * w2;
    a00 += r10 * w3 + r11 * w4 + r12 * w5;
    a00 += r20 * w6 + r21 * w7 + r22 * w8;
    a01 += r01 * w0 + r02 * w1_ + r03 * w2;
    a01 += r11 * w3 + r12 * w4 + r13 * w5;
    a01 += r21 * w6 + r22 * w7 + r23 * w8;
    a10 += r10 * w0 + r11 * w1_ + r12 * w2;
    a10 += r20 * w3 + r21 * w4 + r22 * w5;
    a10 += r30 * w6 + r31 * w7 + r32 * w8;
    a11 += r11 * w0 + r12 * w1_ + r13 * w2;
    a11 += r21 * w3 + r22 * w4 + r23 * w5;
    a11 += r31 * w6 + r32 * w7 + r33 * w8;
  }
  const float bb = bias[co], al = pr[co];
  const bool vx = (x0 + 1 < w1), vy = (y0 + 1 < h1);
  float v = a00 + bb; v = v > 0.f ? v : al * v;
  float m = v;
  if (vx) { v = a01 + bb; v = v > 0.f ? v : al * v; m = fmaxf(m, v); }
  if (vy) { v = a10 + bb; v = v > 0.f ? v : al * v; m = fmaxf(m, v); }
  if (vx && vy) { v = a11 + bb; v = v > 0.f ? v : al * v; m = fmaxf(m, v); }
  out[(((long)b * 10 + co) * PH + py) * PW + px] = m;
}

struct C1P { int nj; int nh[NJMAX]; int imgOff[NJMAX], poolOff[NJMAX];
             int t1x[NJMAX]; int cumT[NJMAX + 1]; };

__global__ void k_conv1pool_job(const float* __restrict__ imgb, const float* __restrict__ w,
                                const float* __restrict__ bias, const float* __restrict__ pr,
                                float* __restrict__ poolb, C1P P) {
  int j = findJob(P.cumT, P.nj, blockIdx.x);
  int local = blockIdx.x - P.cumT[j];
  int t1x = P.t1x[j];
  int tX = local % t1x, tY = local / t1x;
  conv1pool_body(imgb + P.imgOff[j], w, bias, pr, poolb + P.poolOff[j],
                 P.nh[j], P.nh[j], blockIdx.y, blockIdx.z,
                 tX * 16 + (threadIdx.x & 15), tY * 16 + (threadIdx.x >> 4));
}

// ---------------- co-blocked tiled 3x3 conv + PReLU -------------------------
__device__ __forceinline__ void conv3x3c8_body(
    const float* in, const float* w, const float* bias, const float* pr,
    float* out, int Cin, int Cout, int H, int W, int cog, int b, int x0, int y) {
  const int OH = H - 2, OW = W - 2;
  if (y >= OH || x0 >= OW) return;
  float acc[8][4];
#pragma unroll
  for (int k = 0; k < 8; ++k) { acc[k][0] = 0.f; acc[k][1] = 0.f; acc[k][2] = 0.f; acc[k][3] = 0.f; }
  const float* wp = w + (long)cog * Cin * 9;
  const long HW = (long)H * W;
  const float* pp = in + ((long)b * Cin * H + y) * W + x0;
  for (int ci = 0; ci < Cin; ++ci, pp += HW) {
    const float* r = pp;
    float q00 = r[0], q01 = r[1], q02 = r[2], q03 = r[3], q04 = r[4], q05 = r[5]; r += W;
    float q10 = r[0], q11 = r[1], q12 = r[2], q13 = r[3], q14 = r[4], q15 = r[5]; r += W;
    float q20 = r[0], q21 = r[1], q22 = r[2], q23 = r[3], q24 = r[4], q25 = r[5];
#pragma unroll
    for (int k = 0; k < 8; ++k) {
      const float* wc = wp + ((long)k * Cin + ci) * 9;
      float w0 = wc[0], w1 = wc[1], w2 = wc[2];
      float w3 = wc[3], w4 = wc[4], w5 = wc[5];
      float w6 = wc[6], w7 = wc[7], w8 = wc[8];
      acc[k][0] += q00 * w0 + q01 * w1 + q02 * w2;
      acc[k][1] += q01 * w0 + q02 * w1 + q03 * w2;
      acc[k][2] += q02 * w0 + q03 * w1 + q04 * w2;
      acc[k][3] += q03 * w0 + q04 * w1 + q05 * w2;
      acc[k][0] += q10 * w3 + q11 * w4 + q12 * w5;
      acc[k][1] += q11 * w3 + q12 * w4 + q13 * w5;
      acc[k][2] += q12 * w3 + q13 * w4 + q14 * w5;
      acc[k][3] += q13 * w3 + q14 * w4 + q15 * w5;
      acc[k][0] += q20 * w6 + q21 * w7 + q22 * w8;
      acc[k][1] += q21 * w6 + q22 * w7 + q23 * w8;
      acc[k][2] += q22 * w6 + q23 * w7 + q24 * w8;
      acc[k][3] += q23 * w6 + q24 * w7 + q25 * w8;
    }
  }
  const int rem = OW - x0;
#pragma unroll
  for (int k = 0; k < 8; ++k) {
    const int co = cog + k;
    const float bb = bias[co], al = pr[co];
    float* op = out + (((long)b * Cout + co) * OH + y) * OW + x0;
    float v0 = acc[k][0] + bb; v0 = v0 > 0.f ? v0 : al * v0;
    op[0] = v0;
    if (rem > 1) { float v = acc[k][1] + bb; v = v > 0.f ? v : al * v; op[1] = v; }
    if (rem > 2) { float v = acc[k][2] + bb; v = v > 0.f ? v : al * v; op[2] = v; }
    if (rem > 3) { float v = acc[k][3] + bb; v = v > 0.f ? v : al * v; op[3] = v; }
  }
}

struct CvP { int nj; int H[NJMAX]; int inOff[NJMAX], outOff[NJMAX];
             int tx[NJMAX]; int cumT[NJMAX + 1]; };

__global__ void k_conv3x3c8_job(const float* __restrict__ inb, const float* __restrict__ w,
                                const float* __restrict__ bias, const float* __restrict__ pr,
                                float* __restrict__ outb, int Cin, int Cout, CvP P) {
  int j = findJob(P.cumT, P.nj, blockIdx.x);
  int local = blockIdx.x - P.cumT[j];
  int tx0 = P.tx[j];
  int tX = local % tx0, tY = local / tx0;
  conv3x3c8_body(inb + P.inOff[j], w, bias, pr, outb + P.outOff[j], Cin, Cout,
                 P.H[j], P.H[j], blockIdx.y * 8, blockIdx.z,
                 tX * 64 + (threadIdx.x & 15) * 4, tY * 16 + (threadIdx.x >> 4));
}

// ---------------- 1x1 heads -------------------------------------------------
__device__ __forceinline__ void head_body(const float* x3, const float* w41,
                                          const float* b41, const float* w42,
                                          const float* b42, float* reg, u64* keys,
                                          int plane, long idx) {
  int b = (int)(idx / plane); int rem = (int)(idx % plane);
  const float* p = x3 + (long)b * 32 * plane + rem;
  float l0 = 0.f, l1 = 0.f, r0 = 0.f, r1 = 0.f, r2 = 0.f, r3 = 0.f;
  for (int c = 0; c < 32; ++c) {
    float v = p[(long)c * plane];
    l0 += v * w41[c];      l1 += v * w41[32 + c];
    r0 += v * w42[c];      r1 += v * w42[32 + c];
    r2 += v * w42[64 + c]; r3 += v * w42[96 + c];
  }
  l0 += b41[0]; l1 += b41[1];
  r0 += b42[0]; r1 += b42[1]; r2 += b42[2]; r3 += b42[3];
  float mx = fmaxf(l0, l1);
  float e0 = expf(l0 - mx), e1 = expf(l1 - mx);
  float s = e1 / (e0 + e1);
  reg[idx * 4 + 0] = r0; reg[idx * 4 + 1] = r1;
  reg[idx * 4 + 2] = r2; reg[idx * 4 + 3] = r3;
  u32 ic = 0xFFFFFFFFu - (u32)idx;
  u64 k = (s >= 0.6f) ? ((((u64)__float_as_uint(s)) << 32) | ic) : (u64)ic;
  keys[idx] = k;
}

struct HdP { int nj; int h3[NJMAX]; int c3Off[NJMAX], kOff[NJMAX];
             int cumC[NJMAX + 1]; };

__global__ void k_head_job(const float* __restrict__ c3b, const float* __restrict__ w41,
                           const float* __restrict__ b41, const float* __restrict__ w42,
                           const float* __restrict__ b42, float* __restrict__ regb,
                           u64* __restrict__ keysb, HdP P) {
  int gid = blockIdx.x * TPB + threadIdx.x;
  if (gid >= P.cumC[P.nj]) return;
  int j = findJob(P.cumC, P.nj, gid);
  int idx = gid - P.cumC[j];
  head_body(c3b + P.c3Off[j], w41, b41, w42, b42,
            regb + 4L * P.kOff[j], keysb + P.kOff[j], P.h3[j] * P.h3[j], idx);
}

// ---------------- bitonic top-K ---------------------------------------------
__device__ __forceinline__ void bitonic2048(u64* s) {
  for (int k = 2; k <= 2048; k <<= 1) {
    for (int j = k >> 1; j > 0; j >>= 1) {
      for (int i = threadIdx.x; i < 2048; i += TPB) {
        int ixj = i ^ j;
        if (ixj > i) {
          u64 a = s[i], b = s[ixj];
          bool desc = ((i & k) == 0);
          if (desc ? (a < b) : (a > b)) { s[i] = b; s[ixj] = a; }
        }
      }
      __syncthreads();
    }
  }
}

__global__ void k_topk(const u64* __restrict__ in, int n, u64* __restrict__ out, int K) {
  __shared__ u64 s[2048];
  int base = blockIdx.x * 2048;
  for (int t = threadIdx.x; t < 2048; t += TPB) {
    int gi = base + t;
    s[t] = (gi < n) ? in[gi] : 0ULL;
  }
  __syncthreads();
  bitonic2048(s);
  for (int t = threadIdx.x; t < K; t += TPB)
    out[(long)blockIdx.x * K + t] = s[t];
}

struct TkP { int nj; int srcSel[NJMAX]; int srcOff[NJMAX]; int n[NJMAX];
             int dstOff[NJMAX]; int cumB[NJMAX + 1]; };

__global__ void k_topk_job(u64* __restrict__ A, u64* __restrict__ B, TkP P) {
  __shared__ u64 s[2048];
  int j = findJob(P.cumB, P.nj, blockIdx.x);
  int lb = blockIdx.x - P.cumB[j];
  const u64* src = (P.srcSel[j] ? B : A) + P.srcOff[j];
  u64* dst = (P.srcSel[j] ? A : B) + P.dstOff[j];
  int n = P.n[j];
  int base = lb * 2048;
  for (int t = threadIdx.x; t < 2048; t += TPB) {
    int gi = base + t;
    s[t] = (gi < n) ? src[gi] : 0ULL;
  }
  __syncthreads();
  bitonic2048(s);
  for (int t = threadIdx.x; t < 512; t += TPB)
    dst[(long)lb * 512 + t] = s[t];
}

struct TkFP { int nj; int srcSel[NJMAX]; int srcOff[NJMAX]; int n[NJMAX]; int sIdx[NJMAX]; };

__global__ void k_topk_fin(const u64* __restrict__ A, const u64* __restrict__ B,
                           u64* __restrict__ selk, TkFP P) {
  __shared__ u64 s[2048];
  int j = blockIdx.x;
  const u64* src = (P.srcSel[j] ? B : A) + P.srcOff[j];
  int n = P.n[j];
  for (int t = threadIdx.x; t < 2048; t += TPB)
    s[t] = (t < n) ? src[t] : 0ULL;
  __syncthreads();
  bitonic2048(s);
  for (int t = threadIdx.x; t < 512; t += TPB)
    selk[(long)P.sIdx[j] * 512 + t] = s[t];
}

// ---------------- gather box rows -------------------------------------------
__device__ __forceinline__ void gather_body(const u64* keys, const float* reg,
                                            float* boxes, int h, int w, float scalef,
                                            int i) {
  float* bx = boxes + (long)i * 12;
  u64 key = keys[i];
  if ((key >> 32) == 0ULL) {
    for (int q = 0; q < 12; ++q) bx[q] = 0.f;
    return;
  }
  u32 cell = 0xFFFFFFFFu - (u32)(key & 0xFFFFFFFFu);
  int x = (int)(cell % (u32)w); u32 t2 = cell / (u32)w;
  int y = (int)(t2 % (u32)h); int b = (int)(t2 / (u32)h);
  float fx = (float)x, fy = (float)y;
  bx[0] = floorf((2.f * fx + 1.f) / scalef);
  bx[1] = floorf((2.f * fy + 1.f) / scalef);
  bx[2] = floorf((2.f * fx + 12.f) / scalef);
  bx[3] = floorf((2.f * fy + 12.f) / scalef);
  bx[4] = __uint_as_float((u32)(key >> 32));
  bx[5] = reg[(long)cell * 4 + 0];
  bx[6] = reg[(long)cell * 4 + 1];
  bx[7] = reg[(long)cell * 4 + 2];
  bx[8] = reg[(long)cell * 4 + 3];
  bx[9] = (float)b;
  bx[10] = 1.f;
  bx[11] = 0.f;
}

struct GtP { int nj; int h3[NJMAX]; float scalef[NJMAX]; int kOff[NJMAX]; int sIdx[NJMAX]; };

__global__ void k_gather_job(const u64* __restrict__ selk, const float* __restrict__ regb,
                             float* __restrict__ boxes, GtP P) {
  int j = blockIdx.x >> 1;
  int i = ((blockIdx.x & 1) << 8) + threadIdx.x;
  gather_body(selk + (long)P.sIdx[j] * 512, regb + 4L * P.kOff[j],
              boxes + (long)P.sIdx[j] * 512 * 12, P.h3[j], P.h3[j], P.scalef[j], i);
}

// ---------------- greedy NMS ------------------------------------------------
__global__ void k_nms(float* __restrict__ boxes, int per, float thr) {
  __shared__ float sx1[1024], sy1[1024], sx2[1024], sy2[1024], sar[1024];
  __shared__ unsigned char kp[1024];
  __shared__ int snv;
  float* bs = boxes + (long)blockIdx.x * per * 12;
  int N = per;
  if (threadIdx.x == 0) snv = 0;
  __syncthreads();
  for (int i = threadIdx.x; i < N; i += blockDim.x) {
    const float* b = bs + (long)i * 12;
    float off = b[9] * 100000.0f;
    float a0 = b[0] + off, a1 = b[1] + off, a2 = b[2] + off, a3 = b[3] + off;
    sx1[i] = a0; sy1[i] = a1; sx2[i] = a2; sy2[i] = a3;
    sar[i] = fmaxf(a2 - a0, 0.f) * fmaxf(a3 - a1, 0.f);
    bool v = (b[10] != 0.f);
    kp[i] = v;
    if (v) atomicMax(&snv, i + 1);
  }
  __syncthreads();
  int nv = snv;
  for (int i = 0; i < nv; ++i) {
    if (kp[i]) {
      float xi1 = sx1[i], yi1 = sy1[i], xi2 = sx2[i], yi2 = sy2[i], ai = sar[i];
      for (int j = threadIdx.x; j < nv; j += blockDim.x) {
        if (j > i && kp[j]) {
          float iw = fmaxf(fminf(xi2, sx2[j]) - fmaxf(xi1, sx1[j]), 0.f);
          float ih = fmaxf(fminf(yi2, sy2[j]) - fmaxf(yi1, sy1[j]), 0.f);
          float inter = iw * ih;
          float iou = inter / (ai + sar[j] - inter + 1e-9f);
          if (iou > thr) kp[j] = 0;
        }
      }
    }
    __syncthreads();
  }
  for (int i = threadIdx.x; i < N; i += blockDim.x)
    bs[(long)i * 12 + 11] = kp[i] ? 1.f : 0.f;
}

// ---------------- final stage ------------------------------------------------
__global__ void k_finalkeys(const float* __restrict__ boxes, u64* __restrict__ keys,
                            int total, int padded) {
  int i = blockIdx.x * blockDim.x + threadIdx.x;
  if (i >= padded) return;
  u64 k = 0ULL;
  if (i < total) {
    const float* b = boxes + (long)i * 12;
    u32 ic = 0xFFFFFFFFu - (u32)i;
    k = (b[11] != 0.f) ? ((((u64)__float_as_uint(b[4])) << 32) | ic) : (u64)ic;
  }
  keys[i] = k;
}

__global__ void k_gatherfinal(const u64* __restrict__ keys, const float* __restrict__ boxes,
                              float* __restrict__ sel) {
  int i = blockIdx.x * blockDim.x + threadIdx.x;
  if (i >= 1024) return;
  u64 key = keys[i];
  float* o = sel + (long)i * 12;
  if ((key >> 32) == 0ULL) {
    for (int q = 0; q < 12; ++q) o[q] = 0.f;
    return;
  }
  u32 bi = 0xFFFFFFFFu - (u32)(key & 0xFFFFFFFFu);
  const float* b = boxes + (long)bi * 12;
  for (int q = 0; q < 12; ++q) o[q] = b[q];
  o[10] = 1.f;
  o[11] = 0.f;
}

__global__ void k_refine(const float* __restrict__ sel, float* __restrict__ out, int N) {
  int i = blockIdx.x * blockDim.x + threadIdx.x;
  if (i >= N) return;
  const float* b = sel + (long)i * 12;
  float keep = b[11];
  float x1 = b[0], y1 = b[1], x2 = b[2], y2 = b[3], sc = b[4];
  float rw = x2 - x1, rh = y2 - y1;
  float o0 = x1 + b[5] * rw;
  float o1 = y1 + b[6] * rh;
  float o2 = x2 + b[7] * rw;
  float o3 = y2 + b[8] * rh;
  float hh = o3 - o1, ww = o2 - o0;
  float l = fmaxf(hh, ww);
  float nx1 = o0 + ww * 0.5f - l * 0.5f;
  float ny1 = o1 + hh * 0.5f - l * 0.5f;
  out[(long)i * 5 + 0] = nx1 * keep;
  out[(long)i * 5 + 1] = ny1 * keep;
  out[(long)i * 5 + 2] = (nx1 + l) * keep;
  out[(long)i * 5 + 3] = (ny1 + l) * keep;
  out[(long)i * 5 + 4] = sc * keep;
}

extern "C" void kernel_launch(void* const* d_in, const int* in_sizes, int n_in,
                              void* d_out, int out_size, void* d_ws, size_t ws_size,
                              hipStream_t stream) {
  (void)in_sizes; (void)n_in; (void)out_size; (void)ws_size;
  const float* images = (const float*)d_in[0];
  const float* c1w = (const float*)d_in[1];
  const float* c1b = (const float*)d_in[2];
  const float* p1  = (const float*)d_in[3];
  const float* c2w = (const float*)d_in[4];
  const float* c2b = (const float*)d_in[5];
  const float* p2  = (const float*)d_in[6];
  const float* c3w = (const float*)d_in[7];
  const float* c3b = (const float*)d_in[8];
  const float* p3  = (const float*)d_in[9];
  const float* w41 = (const float*)d_in[10];
  const float* b41 = (const float*)d_in[11];
  const float* w42 = (const float*)d_in[12];
  const float* b42 = (const float*)d_in[13];
  float* ws = (float*)d_ws;

  // ---- workspace layout (floats). Region A hosts htmp then (after V) c3. ----
  const long O_HT   = 0;                   // max(htmp G2 15,501,312; c3 13.7M)
  const long O_IMG  = 15501312;            // 5,429,312
  const long O_POOL = O_IMG + 5429312;     // 4,493,360
  const long O_C2   = O_POOL + 4493360;    // 7,013,248
  const long O_REG  = O_C2 + 7013248;      // 1,711,072
  const long O_KEYS = O_REG + 1711072;     // 855,536 (427,768 u64)
  const long O_SCR  = O_KEYS + 855536;     // 218,112 (109,056 u64)
  const long O_SEL  = O_SCR + 218112;      // 11*512 u64
  const long O_BOX  = O_SEL + 11264;       // 5632*12
  const long O_FK   = O_BOX + 67584;       // 8192 u64
  const long O_FS   = O_FK + 16384;        // 1024 u64
  const long O_SF   = O_FS + 2048;         // 1024*12
  const long O_TBL  = O_SF + 12288;        // tables
  const long O_HD   = O_TBL + 12288 + 24000;          // 2 groups x 5 x HDCAP i32
  const long O_VD   = O_HD + 2L * 5 * HDCAP;          // 2 groups x 5 x VDCAP i32

  u64* keys  = (u64*)(ws + O_KEYS);
  u64* scr   = (u64*)(ws + O_SCR);
  u64* selk  = (u64*)(ws + O_SEL);
  u64* fkeys = (u64*)(ws + O_FK);
  u64* fsel  = (u64*)(ws + O_FS);
  float* boxes = ws + O_BOX;
  float* self  = ws + O_SF;
  int*   tX0  = (int*)(ws + O_TBL);
  int*   tCNT = (int*)(ws + O_TBL + 4096);
  float* tWT  = ws + O_TBL + 8192;
  float* tW   = ws + O_TBL + 12288;

  double scl[16]; int nsc = 0;
  {
    double m = 12.0 / 20.0;
    double ml = 768.0 * m;
    double si = m;
    while (ml >= 12.0) { scl[nsc++] = si; si *= 0.709; ml *= 0.709; }
  }

  auto cdiv = [](long a, long b) { return (int)((a + b - 1) / b); };

  // per-scale dims + table geometry
  int NH[NSC], PH_[NSC], H2[NSC], H3[NSC], OXB[NSC], TT[NSC], WOFF[NSC];
  float INV[NSC], KSF[NSC];
  {
    int oxb = 0, woff = 0;
    for (int s = 0; s < nsc; ++s) {
      int nh = (int)(768.0 * scl[s] + 1.0);
      NH[s] = nh;
      PH_[s] = ((nh - 2) + 1) / 2;
      H2[s] = PH_[s] - 2;
      H3[s] = H2[s] - 2;
      double inv = 1.0 / (((double)nh) / 768.0);
      INV[s] = (float)inv;
      KSF[s] = (float)(inv > 1.0 ? inv : 1.0);
      TT[s] = (int)(2.0f * KSF[s]) + 2;
      OXB[s] = oxb; oxb += nh;
      WOFF[s] = woff; woff += nh * TT[s];
    }
  }

  // build resize weight tables (once per launch)
  {
    MkP P; P.ns = nsc;
    for (int s = 0; s < nsc; ++s) {
      P.nw[s] = NH[s]; P.invs[s] = INV[s]; P.ks[s] = KSF[s];
      P.oxB[s] = OXB[s]; P.T[s] = TT[s]; P.wOff[s] = WOFF[s];
    }
    k_mkweights<<<nsc, TPB, 0, stream>>>(tX0, tCNT, tWT, tW, P);
  }

  const int G1[7] = {0, 5, 6, 7, 8, 9, 10};
  const int G2[4] = {1, 2, 3, 4};
  const int* GS[2] = {G1, G2};
  const int GN[2] = {7, 4};

  // per-group geometry (host-side, reused by mkdesc + pipeline)
  int htmpOff[2][NJMAX], imgOff[2][NJMAX], poolOff[2][NJMAX], c2Off[2][NJMAX],
      c3Off[2][NJMAX], kOff[2][NJMAX], cells[2][NJMAX];
  int cumWtot[2], cumRtot[2];
  for (int g = 0; g < 2; ++g) {
    long ch = 0, ci = 0, cp = 0, c2 = 0, c3 = 0, ck = 0;
    int cw = 0, cr = 0;
    for (int q = 0; q < GN[g]; ++q) {
      int s = GS[g][q];
      htmpOff[g][q] = (int)ch; ch += 24L * 768 * NH[s];
      imgOff[g][q]  = (int)ci; ci += 24L * NH[s] * NH[s];
      poolOff[g][q] = (int)cp; cp += 80L * PH_[s] * PH_[s];
      c2Off[g][q]   = (int)c2; c2 += 128L * H2[s] * H2[s];
      c3Off[g][q]   = (int)c3; c3 += 256L * H3[s] * H3[s];
      kOff[g][q]    = (int)ck; cells[g][q] = 8 * H3[s] * H3[s]; ck += cells[g][q];
      cw += 3 * NH[s]; cr += 24 * NH[s];
    }
    cumWtot[g] = cw; cumRtot[g] = cr;
  }

  // build H/V descriptors (geometry-only)
  for (int g = 0; g < 2; ++g) {
    DscP P; P.nj = GN[g];
    int cw = 0, cr = 0;
    for (int q = 0; q < GN[g]; ++q) {
      int s = GS[g][q];
      P.N[q] = NH[s]; P.hOff[q] = htmpOff[g][q]; P.imgOff[q] = imgOff[g][q];
      P.oxB[q] = OXB[s]; P.wOff[q] = WOFF[s];
      P.cumW[q] = cw; cw += 3 * NH[s];
      P.cumR[q] = cr; cr += 24 * NH[s];
    }
    P.cumW[GN[g]] = cw; P.cumR[GN[g]] = cr;
    int* hd = (int*)(ws + O_HD) + (long)g * 5 * HDCAP;
    int* vd = (int*)(ws + O_VD) + (long)g * 5 * VDCAP;
    int tot = cw > cr ? cw : cr;
    k_mkdesc<<<cdiv(tot, TPB), TPB, 0, stream>>>(hd, vd, P);
  }

  // ---------------- unified job pipeline, two scale groups ----------------
  auto runGroup = [&](int g) {
    const int* gs = GS[g];
    int nj = GN[g];
    int* hd = (int*)(ws + O_HD) + (long)g * 5 * HDCAP;
    int* vd = (int*)(ws + O_VD) + (long)g * 5 * VDCAP;
    // H pass (one image read for the whole group)
    {
      dim3 gh(768, 8, 1);
      k_resizeH_d<<<gh, TPB, 0, stream>>>(images, ws + O_HT, tX0, tCNT, tWT, tW,
                                          hd, cumWtot[g]);
    }
    // V pass: one wave per output row
    k_resizeV_row<<<cdiv(cumRtot[g], 4), TPB, 0, stream>>>(
        ws + O_HT, ws + O_IMG, tX0, tCNT, tWT, tW, vd, cumRtot[g]);
    // conv1+pool
    {
      C1P P; P.nj = nj; int ct = 0;
      for (int q = 0; q < nj; ++q) {
        int s = gs[q];
        P.nh[q] = NH[s];
        P.imgOff[q] = imgOff[g][q]; P.poolOff[q] = poolOff[g][q];
        int t1x = cdiv(PH_[s], 16);
        P.t1x[q] = t1x;
        P.cumT[q] = ct; ct += t1x * t1x;
      }
      P.cumT[nj] = ct;
      dim3 gg(ct, 10, 8);
      k_conv1pool_job<<<gg, TPB, 0, stream>>>(ws + O_IMG, c1w, c1b, p1, ws + O_POOL, P);
    }
    // conv2
    {
      CvP P; P.nj = nj; int ct = 0;
      for (int q = 0; q < nj; ++q) {
        int s = gs[q];
        P.H[q] = PH_[s];
        P.inOff[q] = poolOff[g][q]; P.outOff[q] = c2Off[g][q];
        int tx = cdiv(H2[s], 64), ty = cdiv(H2[s], 16);
        P.tx[q] = tx;
        P.cumT[q] = ct; ct += tx * ty;
      }
      P.cumT[nj] = ct;
      dim3 gg(ct, 2, 8);
      k_conv3x3c8_job<<<gg, TPB, 0, stream>>>(ws + O_POOL, c2w, c2b, p2, ws + O_C2,
                                              10, 16, P);
    }
    // conv3 (writes into region A; htmp is dead after V pass)
    {
      CvP P; P.nj = nj; int ct = 0;
      for (int q = 0; q < nj; ++q) {
        int s = gs[q];
        P.H[q] = H2[s];
        P.inOff[q] = c2Off[g][q]; P.outOff[q] = c3Off[g][q];
        int tx = cdiv(H3[s], 64), ty = cdiv(H3[s], 16);
        P.tx[q] = tx;
        P.cumT[q] = ct; ct += tx * ty;
      }
      P.cumT[nj] = ct;
      dim3 gg(ct, 4, 8);
      k_conv3x3c8_job<<<gg, TPB, 0, stream>>>(ws + O_C2, c3w, c3b, p3, ws + O_HT,
                                              16, 32, P);
    }
    // heads
    {
      HdP P; P.nj = nj; int cc = 0;
      for (int q = 0; q < nj; ++q) {
        int s = gs[q];
        P.h3[q] = H3[s];
        P.c3Off[q] = c3Off[g][q]; P.kOff[q] = kOff[g][q];
        P.cumC[q] = cc; cc += cells[g][q];
      }
      P.cumC[nj] = cc;
      k_head_job<<<cdiv(cc, TPB), TPB, 0, stream>>>(ws + O_HT, w41, b41, w42, b42,
                                                    ws + O_REG, keys, P);
    }
    // batched top-512 tournament
    {
      int bOff[NJMAX];
      {
        int c = 0;
        for (int q = 0; q < nj; ++q) { bOff[q] = c; c += 512 * cdiv(cells[g][q], 2048); }
      }
      long nCur[NJMAX]; int par[NJMAX];
      for (int q = 0; q < nj; ++q) { nCur[q] = cells[g][q]; par[q] = 0; }
      while (true) {
        TkP P; P.nj = 0; int cum = 0; int act[NJMAX];
        for (int q = 0; q < nj; ++q) {
          if (nCur[q] > 2048) {
            int r = P.nj++;
            act[r] = q;
            int blocks = cdiv(nCur[q], 2048);
            P.srcSel[r] = par[q];
            P.srcOff[r] = par[q] ? bOff[q] : kOff[g][q];
            P.dstOff[r] = par[q] ? kOff[g][q] : bOff[q];
            P.n[r] = (int)nCur[q];
            P.cumB[r] = cum; cum += blocks;
          }
        }
        P.cumB[P.nj] = cum;
        if (P.nj == 0) break;
        k_topk_job<<<cum, TPB, 0, stream>>>(keys, scr, P);
        for (int r = 0; r < P.nj; ++r) {
          int q = act[r];
          nCur[q] = 512L * cdiv(nCur[q], 2048);
          par[q] ^= 1;
        }
      }
      TkFP F; F.nj = nj;
      for (int q = 0; q < nj; ++q) {
        F.srcSel[q] = par[q];
        F.srcOff[q] = par[q] ? bOff[q] : kOff[g][q];
        F.n[q] = (int)nCur[q];
        F.sIdx[q] = gs[q];
      }
      k_topk_fin<<<nj, TPB, 0, stream>>>(keys, scr, selk, F);
    }
    // gather
    {
      GtP P; P.nj = nj;
      for (int q = 0; q < nj; ++q) {
        int s = gs[q];
        P.h3[q] = H3[s]; P.scalef[q] = (float)scl[s]; P.kOff[q] = kOff[g][q];
        P.sIdx[q] = s;
      }
      k_gather_job<<<2 * nj, TPB, 0, stream>>>(selk, ws + O_REG, boxes, P);
    }
  };

  runGroup(0);
  runGroup(1);

  // ---------------- per-scale NMS + final stage ----------------
  k_nms<<<nsc, TPB, 0, stream>>>(boxes, 512, 0.5f);

  int total = nsc * 512;
  k_finalkeys<<<cdiv(8192, TPB), TPB, 0, stream>>>(boxes, fkeys, total, 8192);
  k_topk<<<4, TPB, 0, stream>>>(fkeys, 8192, scr, 1024);
  k_topk<<<2, TPB, 0, stream>>>(scr, 4096, keys, 1024);
  k_topk<<<1, TPB, 0, stream>>>(keys, 2048, fsel, 1024);
  k_gatherfinal<<<4, TPB, 0, stream>>>(fsel, boxes, self);
  k_nms<<<1, TPB, 0, stream>>>(self, 1024, 0.7f);
  k_refine<<<4, TPB, 0, stream>>>(self, (float*)d_out, 1024);
}